// Round 4
// baseline (1222.269 us; speedup 1.0000x reference)
//
#include <hip/hip_runtime.h>

#define B_    2
#define L_    1024
#define D_    768
#define H_    12
#define DH_   64
#define DP_   32
#define MLP_  3072
#define NL_   4
#define WIN_  128
#define W2_   257            // window columns (rel = j-i+128 in [0,256])
#define M_    (B_*L_)        // 2048 rows

typedef __attribute__((ext_vector_type(8))) short bf16x8;
typedef __attribute__((ext_vector_type(4))) float f32x4;

__device__ __forceinline__ unsigned short f2bf(float x){
  unsigned int u = __float_as_uint(x);
  u += 0x7fffu + ((u >> 16) & 1u);   // RNE; inputs finite
  return (unsigned short)(u >> 16);
}

__device__ __forceinline__ void gl_lds16(const void* g, void* l){
  __builtin_amdgcn_global_load_lds((__attribute__((address_space(1))) void*)g,
                                   (__attribute__((address_space(3))) void*)l, 16, 0, 0);
}

// ---------------- fused prologue: pair-bias + rope table + all weight cvt ----------------
// block ranges: [0,2056) pair_bias | [2056,2184) rope table | [2184,29832) weight cvt
#define PB_BLKS_   2056
#define RT_BLKS_   128
#define CVT_Q0_    1769472    // qkv_w quads (4*2304*768/4)
#define CVT_Q1_    2359296    // + out_w quads
#define CVT_Q2_    4718592    // + fc1_w quads
#define CVT_Q3_    7077888    // + fc2_w quads (total)
__global__ __launch_bounds__(256) void prologue_k(
    const float* __restrict__ pair, const float* __restrict__ ln_g,
    const float* __restrict__ ln_b, const float* __restrict__ pb_w,
    const float* __restrict__ pb_b, float* __restrict__ bias,
    float2* __restrict__ rtab,
    const float* __restrict__ qkv_w, const float* __restrict__ out_w,
    const float* __restrict__ fc1_w, const float* __restrict__ fc2_w,
    unsigned short* __restrict__ wall){
  __shared__ float gw[NL_][DP_];
  __shared__ float cb[NL_];
  const int bid = blockIdx.x, tid = threadIdx.x;
  if (bid < PB_BLKS_){
    // ---- pair bias: LN(pair)@pb_w + pb_b for ALL layers, window only ----
    if (tid < NL_*DP_) gw[tid>>5][tid&31] = ln_g[tid]*pb_w[tid];
    if (tid < NL_){
      float c = 0.f;
      for (int d=0; d<DP_; ++d) c += ln_b[tid*DP_+d]*pb_w[tid*DP_+d];
      cb[tid] = c + pb_b[tid];
    }
    __syncthreads();
    int idx = bid*256 + tid;
    if (idx >= B_*L_*W2_) return;
    int rel = idx % W2_;
    int t   = idx / W2_;
    int i   = t & (L_-1);
    int b   = t >> 10;
    int j   = i + rel - WIN_;
    if (j < 0 || j >= L_) return;            // never read by attention
    const float4* p = (const float4*)(pair + ((size_t)(b*L_ + i)*L_ + j)*DP_);
    float4 x[8];
    #pragma unroll
    for (int q=0;q<8;++q) x[q] = p[q];
    float s=0.f, ss=0.f;
    #pragma unroll
    for (int q=0;q<8;++q){
      s  += x[q].x + x[q].y + x[q].z + x[q].w;
      ss += x[q].x*x[q].x + x[q].y*x[q].y + x[q].z*x[q].z + x[q].w*x[q].w;
    }
    float m  = s * (1.0f/DP_);
    float rs = rsqrtf(ss*(1.0f/DP_) - m*m + 1e-5f);
    #pragma unroll
    for (int l=0;l<NL_;++l){
      float acc = 0.f;
      #pragma unroll
      for (int q=0;q<8;++q){
        acc += (x[q].x-m)*gw[l][4*q+0] + (x[q].y-m)*gw[l][4*q+1]
             + (x[q].z-m)*gw[l][4*q+2] + (x[q].w-m)*gw[l][4*q+3];
      }
      bias[(((size_t)l*B_ + b)*L_ + i)*W2_ + rel] = acc*rs + cb[l];
    }
  } else if (bid < PB_BLKS_ + RT_BLKS_){
    // ---- rope cos/sin table [L][32] ----
    int idx = (bid - PB_BLKS_)*256 + tid;
    int t = idx & 31, i = idx >> 5;
    float invf = expf(-(float)t * 0.28782313662425572f);   // ln(10000)/32
    float ang = (float)i * invf;
    float sn, cs;
    sincosf(ang, &sn, &cs);
    rtab[idx] = make_float2(cs, sn);
  } else {
    // ---- f32 -> bf16 weight conversion (all four weight tensors) ----
    size_t q = (size_t)(bid - PB_BLKS_ - RT_BLKS_)*256 + tid;
    const float* src; unsigned short* dst; size_t ql;
    if (q < CVT_Q0_)      { ql = q;            src = qkv_w; dst = wall; }
    else if (q < CVT_Q1_) { ql = q - CVT_Q0_;  src = out_w; dst = wall + (size_t)CVT_Q0_*4; }
    else if (q < CVT_Q2_) { ql = q - CVT_Q1_;  src = fc1_w; dst = wall + (size_t)CVT_Q1_*4; }
    else                  { ql = q - CVT_Q2_;  src = fc2_w; dst = wall + (size_t)CVT_Q2_*4; }
    float4 v = ((const float4*)src)[ql];
    ushort4 o;
    o.x = f2bf(v.x); o.y = f2bf(v.y); o.z = f2bf(v.z); o.w = f2bf(v.w);
    ((ushort4*)dst)[ql] = o;
  }
}

// ---------------- bf16 GEMM: C[M,N] = A[M,K] @ W[N,K]^T + bias, fused epilogues ----
// RMSA=1 (TM=128 only): A is f32 residual s[M,768]; block computes rmsnorm scales for
//   its 128 rows in a prologue, then reg-stages A tiles (load f32 -> *rs -> bf16 -> LDS).
// MODE 0: qkv — q,k get RoPE applied in-register (partner col+32 is acc[mi][ni+2]),
//         written bf16 to outq/outk in [bh][i][64]; v cols -> outb bf16 [bh][j][64].
// MODE 1: resid += C          (attn out proj)
// MODE 2: outb = bf16(gelu(C))(fc1)
// MODE 3: resid += C          (fc2)
// TM: 128 or 64 (M rows per block). SPLIT: split-K factor (atomicAdd epilogue if >1).
template<int MODE, int TM, int SPLIT, int RMSA>
__global__ __launch_bounds__(256) void gemm_bt(const unsigned short* __restrict__ A,
    const float* __restrict__ Af,
    const unsigned short* __restrict__ W, const float* __restrict__ bias,
    unsigned short* __restrict__ outb, float* __restrict__ resid,
    unsigned short* __restrict__ outq, unsigned short* __restrict__ outk,
    const float2* __restrict__ rtab, int N, int K){
  constexpr int MI = TM/32;
  __shared__ __align__(16) short sm[2][(TM+128)*32];
  const int tid  = threadIdx.x;
  const int wave = tid >> 6, lane = tid & 63;
  const int m0 = blockIdx.y*TM, n0 = blockIdx.x << 7;
  const int KB = K / SPLIT;
  const int kbase = blockIdx.z * KB;
  const int wm = (wave >> 1)*(TM/2), wn = (wave & 1) << 6;
  const int lrow = lane & 15, ko = (lane >> 4) << 3;
  f32x4 acc[MI][4] = {};
  const unsigned short* Wg = W + (size_t)(n0 + (tid>>2))*K + kbase + ((tid&3)<<3);
  const size_t hstep = (size_t)64*K;
  const int nk = KB >> 5;

  float rs = 0.f;
  const float* Ab = nullptr;
  const unsigned short* Ag = nullptr;
  if constexpr (RMSA){
    // rmsnorm prologue: thread owns row (tid>>1), half (tid&1) of 768
    const int ar = tid >> 1, half = tid & 1;
    const float* rowp = Af + (size_t)(m0 + ar)*D_ + half*(D_/2);
    float s0=0.f, s1=0.f, s2=0.f, s3=0.f;
    #pragma unroll 4
    for (int q=0;q<24;++q){
      float4 v0=((const float4*)rowp)[4*q+0], v1=((const float4*)rowp)[4*q+1];
      float4 v2=((const float4*)rowp)[4*q+2], v3=((const float4*)rowp)[4*q+3];
      s0 += v0.x*v0.x + v0.y*v0.y + v0.z*v0.z + v0.w*v0.w;
      s1 += v1.x*v1.x + v1.y*v1.y + v1.z*v1.z + v1.w*v1.w;
      s2 += v2.x*v2.x + v2.y*v2.y + v2.z*v2.z + v2.w*v2.w;
      s3 += v3.x*v3.x + v3.y*v3.y + v3.z*v3.z + v3.w*v3.w;
    }
    float ssum = (s0+s1)+(s2+s3);
    ssum += __shfl_xor(ssum, 1, 64);
    rs = rsqrtf(ssum*(1.0f/D_) + 1.1920929e-07f);
    Ab = Af + (size_t)(m0 + ar)*D_ + half*16;
  } else {
    Ag = A + (size_t)(m0 + (tid>>2))*K + kbase + ((tid&3)<<3);
  }

  float4 pa[4];
  auto loadA = [&](int kt){
    pa[0] = *(const float4*)(Ab + kt);
    pa[1] = *(const float4*)(Ab + kt + 4);
    pa[2] = *(const float4*)(Ab + kt + 8);
    pa[3] = *(const float4*)(Ab + kt + 12);
  };
  auto writeA = [&](short* As){
    bf16x8 w0, w1;
    w0[0]=(short)f2bf(pa[0].x*rs); w0[1]=(short)f2bf(pa[0].y*rs);
    w0[2]=(short)f2bf(pa[0].z*rs); w0[3]=(short)f2bf(pa[0].w*rs);
    w0[4]=(short)f2bf(pa[1].x*rs); w0[5]=(short)f2bf(pa[1].y*rs);
    w0[6]=(short)f2bf(pa[1].z*rs); w0[7]=(short)f2bf(pa[1].w*rs);
    w1[0]=(short)f2bf(pa[2].x*rs); w1[1]=(short)f2bf(pa[2].y*rs);
    w1[2]=(short)f2bf(pa[2].z*rs); w1[3]=(short)f2bf(pa[2].w*rs);
    w1[4]=(short)f2bf(pa[3].x*rs); w1[5]=(short)f2bf(pa[3].y*rs);
    w1[6]=(short)f2bf(pa[3].z*rs); w1[7]=(short)f2bf(pa[3].w*rs);
    short* d = &As[(tid>>1)*32 + (tid&1)*16];
    *(bf16x8*)(d)     = w0;
    *(bf16x8*)(d + 8) = w1;
  };

  {  // prologue stage into buf 0
    short* As = sm[0]; short* Bs = sm[0] + TM*32;
    if constexpr (RMSA){
      loadA(0); writeA(As);
    } else {
      gl_lds16(Ag, &As[tid*8]);
      if (TM == 128) gl_lds16(Ag + hstep, &As[(tid+256)*8]);
    }
    gl_lds16(Wg, &Bs[tid*8]);
    gl_lds16(Wg + hstep, &Bs[(tid+256)*8]);
  }
  for (int it = 0; it < nk; ++it){
    __syncthreads();                       // drains vmcnt+lgkm -> buf (it&1) ready
    const bool pf = (it + 1 < nk);
    if (pf){                               // prefetch next tile, overlaps MFMA below
      short* As = sm[(it&1)^1]; short* Bs = As + TM*32;
      const int kt = (it+1) << 5;
      if constexpr (RMSA){
        loadA(kt);                         // global f32 loads in flight during MFMA
      } else {
        gl_lds16(Ag + kt, &As[tid*8]);
        if (TM == 128) gl_lds16(Ag + hstep + kt, &As[(tid+256)*8]);
      }
      gl_lds16(Wg + kt, &Bs[tid*8]);
      gl_lds16(Wg + hstep + kt, &Bs[(tid+256)*8]);
    }
    const short* As = sm[it&1]; const short* Bs = As + TM*32;
    bf16x8 af[MI], bv[4];
    #pragma unroll
    for (int i=0;i<MI;++i) af[i] = *(const bf16x8*)&As[((wm + i*16 + lrow) << 5) + ko];
    #pragma unroll
    for (int i=0;i<4;++i)  bv[i] = *(const bf16x8*)&Bs[((wn + i*16 + lrow) << 5) + ko];
    #pragma unroll
    for (int mi=0;mi<MI;++mi)
      #pragma unroll
      for (int ni=0;ni<4;++ni)
        acc[mi][ni] = __builtin_amdgcn_mfma_f32_16x16x32_bf16(af[mi], bv[ni], acc[mi][ni], 0, 0, 0);
    if (RMSA && pf) writeA(sm[(it&1)^1]); // scale+cvt+LDS-write after MFMA issue
  }
  if (MODE == 0){
    // rope-fused epilogue: process (ni, ni+2) pairs = (d, d+32) of one head
    #pragma unroll
    for (int ni=0; ni<2; ++ni){
      const int col0 = n0 + wn + ni*16 + lrow;       // d = d0 in [0,32)
      const int d0 = ni*16 + lrow;
      const float b0 = bias[col0], b2 = bias[col0 + 32];
      #pragma unroll
      for (int mi=0; mi<MI; ++mi){
        const int rw = m0 + wm + mi*16 + ((lane >> 4) << 2);
        #pragma unroll
        for (int r=0; r<4; ++r){
          const int rowg = rw + r;
          const int bI = rowg >> 10, iI = rowg & (L_-1);
          const float v0 = acc[mi][ni][r]   + b0;
          const float v2 = acc[mi][ni+2][r] + b2;
          if (col0 < 2*D_){
            const bool isq = (col0 < D_);
            const int  h   = (isq ? col0 : col0 - D_) >> 6;
            const float2 cssn = rtab[iI*32 + d0];
            const float o0 = v0*cssn.x - v2*cssn.y;   // d<32: q*c - q[d+32]*s
            const float o2 = v2*cssn.x + v0*cssn.y;   // d>=32: q*c + q[d-32]*s
            unsigned short* dst = (isq ? outq : outk)
                + ((((size_t)(bI*H_ + h)) << 10 | iI) << 6);
            dst[d0]      = f2bf(o0);
            dst[d0 + 32] = f2bf(o2);
          } else {
            const int h = (col0 - 2*D_) >> 6;
            unsigned short* dst = outb + ((((size_t)(bI*H_ + h)) << 10 | iI) << 6);
            dst[d0]      = f2bf(v0);
            dst[d0 + 32] = f2bf(v2);
          }
        }
      }
    }
  } else {
    #pragma unroll
    for (int ni=0;ni<4;++ni){
      const int col = n0 + wn + ni*16 + lrow;
      const float bb = (SPLIT == 1 || blockIdx.z == 0) ? bias[col] : 0.f;
      #pragma unroll
      for (int mi=0;mi<MI;++mi){
        const int rw = m0 + wm + mi*16 + ((lane >> 4) << 2);
        #pragma unroll
        for (int r=0;r<4;++r){
          float v = acc[mi][ni][r] + bb;
          if (MODE == 2){
            float g = 0.5f * v * (1.0f + erff(v * 0.70710678118654752f));
            outb[(size_t)(rw + r)*N + col] = f2bf(g);
          } else {
            if (SPLIT == 1) resid[(size_t)(rw + r)*D_ + col] += v;
            else            atomicAdd(&resid[(size_t)(rw + r)*D_ + col], v);
          }
        }
      }
    }
  }
}

// ---------------- windowed MFMA attention, 32-query tiles ----------------
// Per block: one (bh, 32-query tile). K-strip of 288 keys staged bf16 in LDS
// (precomputed bf16 K, no conversion), QK^T and PV via 16x16x32 bf16 MFMA.
// V (precomputed bf16) reuses the K buffer after softmax.
__global__ __launch_bounds__(256) void attn_k(const unsigned short* __restrict__ qr,
    const unsigned short* __restrict__ kr, const unsigned short* __restrict__ vr,
    const float* __restrict__ bias, unsigned short* __restrict__ ybf, int layer){
  __shared__ __align__(16) short kb[288*72];   // K then V, row stride 72 (+8 pad) = 41472 B
  __shared__ __align__(16) float sc[32*304];   // scores f32; probs bf16 alias below
  short* ps = (short*)sc;                      // [32][296] bf16 (stride 296: conflict-free b128)
  const int tid  = threadIdx.x;
  const int wave = tid >> 6, lane = tid & 63;
  const int quad = lane >> 4, lrow = lane & 15;
  const int bh = blockIdx.y, b = bh / H_, h = bh - b*H_;
  const int i0 = blockIdx.x * 32, jb = i0 - WIN_;

  // Q fragments for both 16-row m-tiles: A[m=lrow][k=quad*8+j], two K=32 halves
  bf16x8 qf[2][2];
  #pragma unroll
  for (int mt=0; mt<2; ++mt){
    const unsigned short* qrow = qr + (((size_t)bh*L_ + i0 + mt*16 + lrow) << 6) + quad*8;
    qf[mt][0] = *(const bf16x8*)qrow;
    qf[mt][1] = *(const bf16x8*)(qrow + 32);
  }
  // stage K strip (288 rows x 64 bf16), zero-filled outside [0,L)
  {
    const int r0 = tid >> 3, seg = tid & 7;
    #pragma unroll
    for (int p=0; p<9; ++p){
      const int r = r0 + p*32;
      const int jg = jb + r;
      bf16x8 z;
      #pragma unroll
      for (int q=0;q<8;++q) z[q] = 0;
      if ((unsigned)jg < L_) z = *(const bf16x8*)(kr + (((size_t)bh*L_ + jg) << 6) + seg*8);
      *(bf16x8*)&kb[r*72 + seg*8] = z;
    }
  }
  __syncthreads();
  // QK^T: 18 key-chunks of 16, round-robin over waves; each wave does both m-tiles
  for (int c = wave; c < 18; c += 4){
    const int krow = c*16 + lrow;
    const bf16x8 kf0 = *(const bf16x8*)&kb[krow*72 + quad*8];
    const bf16x8 kf1 = *(const bf16x8*)&kb[krow*72 + 32 + quad*8];
    const int jj = c*16 + lrow, jg = jb + jj;
    #pragma unroll
    for (int mt=0; mt<2; ++mt){
      f32x4 cc = {0.f,0.f,0.f,0.f};
      cc = __builtin_amdgcn_mfma_f32_16x16x32_bf16(qf[mt][0], kf0, cc, 0, 0, 0);
      cc = __builtin_amdgcn_mfma_f32_16x16x32_bf16(qf[mt][1], kf1, cc, 0, 0, 0);
      #pragma unroll
      for (int r=0;r<4;++r){
        const int row = mt*16 + quad*4 + r;
        const int rel = jj - row;             // j - i + 128
        float v = -1e30f;
        if (rel >= 0 && rel <= 256 && (unsigned)jg < L_)
          v = cc[r]*0.125f + bias[(((size_t)(layer*B_ + b))*L_ + i0 + row)*W2_ + rel];
        sc[row*304 + jj] = v;
      }
    }
  }
  __syncthreads();
  // softmax: thread group of 16 handles rows qq and qq+16
  const int qq = tid >> 4, tj = tid & 15;
  float ev[2][18];
  #pragma unroll
  for (int g=0; g<2; ++g)
    #pragma unroll
    for (int c=0;c<18;++c) ev[g][c] = sc[(qq + g*16)*304 + c*16 + tj];
  __syncthreads();                 // all sc reads done before ps alias-writes
  #pragma unroll
  for (int g=0; g<2; ++g){
    float mx = -3.0e38f;
    #pragma unroll
    for (int c=0;c<18;++c) mx = fmaxf(mx, ev[g][c]);
    #pragma unroll
    for (int m=1; m<16; m<<=1) mx = fmaxf(mx, __shfl_xor(mx, m, 16));
    float sm = 0.f;
    #pragma unroll
    for (int c=0;c<18;++c){ float e = __expf(ev[g][c] - mx); ev[g][c] = e; sm += e; }
    #pragma unroll
    for (int m=1; m<16; m<<=1) sm += __shfl_xor(sm, m, 16);
    const float inv = 1.0f / sm;
    #pragma unroll
    for (int c=0;c<18;++c) ps[(qq + g*16)*296 + c*16 + tj] = (short)f2bf(ev[g][c]*inv);
  }
  // stage V into kb (zero-fill: ps~0 rows must not meet inf/NaN)
  {
    const int r0 = tid >> 3, seg = tid & 7;
    #pragma unroll
    for (int p=0; p<9; ++p){
      const int r = r0 + p*32;
      const int jg = jb + r;
      bf16x8 z;
      #pragma unroll
      for (int q=0;q<8;++q) z[q] = 0;
      if ((unsigned)jg < L_) z = *(const bf16x8*)(vr + (((size_t)bh*L_ + jg) << 6) + seg*8);
      *(bf16x8*)&kb[r*72 + seg*8] = z;
    }
  }
  __syncthreads();
  // PV: O[32][64] = P[32x288] @ V[288x64]; wave owns d-tile [wave*16, wave*16+16)
  f32x4 o0 = {0.f,0.f,0.f,0.f}, o1 = {0.f,0.f,0.f,0.f};
  for (int kc=0; kc<9; ++kc){
    bf16x8 bf;
    #pragma unroll
    for (int j=0;j<8;++j) bf[j] = kb[(kc*32 + quad*8 + j)*72 + wave*16 + lrow];
    const bf16x8 a0 = *(const bf16x8*)&ps[lrow*296 + kc*32 + quad*8];
    const bf16x8 a1 = *(const bf16x8*)&ps[(16 + lrow)*296 + kc*32 + quad*8];
    o0 = __builtin_amdgcn_mfma_f32_16x16x32_bf16(a0, bf, o0, 0, 0, 0);
    o1 = __builtin_amdgcn_mfma_f32_16x16x32_bf16(a1, bf, o1, 0, 0, 0);
  }
  #pragma unroll
  for (int r=0;r<4;++r){
    const int row = quad*4 + r;
    ybf[((size_t)(b*L_ + i0 + row))*D_ + h*64 + wave*16 + lrow]      = f2bf(o0[r]);
    ybf[((size_t)(b*L_ + i0 + 16 + row))*D_ + h*64 + wave*16 + lrow] = f2bf(o1[r]);
  }
}

extern "C" void kernel_launch(void* const* d_in, const int* in_sizes, int n_in,
                              void* d_out, int out_size, void* d_ws, size_t ws_size,
                              hipStream_t stream){
  (void)in_sizes; (void)n_in; (void)out_size; (void)ws_size;
  const float* s_in  = (const float*)d_in[0];
  const float* pair  = (const float*)d_in[1];
  const float* qkv_w = (const float*)d_in[2];
  const float* qkv_b = (const float*)d_in[3];
  const float* out_w = (const float*)d_in[4];
  const float* out_b = (const float*)d_in[5];
  const float* fc1_w = (const float*)d_in[6];
  const float* fc1_b = (const float*)d_in[7];
  const float* fc2_w = (const float*)d_in[8];
  const float* fc2_b = (const float*)d_in[9];
  const float* ln_g  = (const float*)d_in[10];
  const float* ln_b  = (const float*)d_in[11];
  const float* pb_w  = (const float*)d_in[12];
  const float* pb_b  = (const float*)d_in[13];
  float* s = (float*)d_out;                    // residual stream lives in d_out

  char* ws = (char*)d_ws;
  size_t off = 0;
  auto take = [&](size_t bytes)->char*{
    char* p = ws + off; off += (bytes + 255) & ~(size_t)255; return p;
  };
  // NOTE: wqkv..wfc2 must stay contiguous (prologue_k writes via one base ptr);
  // all four sizes are exact multiples of 256 B.
  unsigned short* wqkv = (unsigned short*)take((size_t)NL_*3*D_*D_*2);
  unsigned short* wout = (unsigned short*)take((size_t)NL_*D_*D_*2);
  unsigned short* wfc1 = (unsigned short*)take((size_t)NL_*MLP_*D_*2);
  unsigned short* wfc2 = (unsigned short*)take((size_t)NL_*D_*MLP_*2);
  float*          bw   = (float*)take((size_t)NL_*B_*L_*W2_*4);
  unsigned short* qrb  = (unsigned short*)take((size_t)B_*H_*L_*DH_*2);
  unsigned short* krb  = (unsigned short*)take((size_t)B_*H_*L_*DH_*2);
  unsigned short* vrb  = (unsigned short*)take((size_t)B_*H_*L_*DH_*2);
  unsigned short* ybf  = (unsigned short*)take((size_t)M_*D_*2);
  unsigned short* gbf  = (unsigned short*)take((size_t)M_*MLP_*2);
  float2*         rtab = (float2*)take((size_t)L_*32*sizeof(float2));

  hipMemcpyAsync(s, s_in, (size_t)M_*D_*sizeof(float), hipMemcpyDeviceToDevice, stream);

  prologue_k<<<PB_BLKS_ + RT_BLKS_ + CVT_Q3_/256, 256, 0, stream>>>(
      pair, ln_g, ln_b, pb_w, pb_b, bw, rtab,
      qkv_w, out_w, fc1_w, fc2_w, wqkv);

  for (int l=0; l<NL_; ++l){
    gemm_bt<0,128,1,1><<<dim3((3*D_)/128, M_/128), 256, 0, stream>>>(
        nullptr, s, wqkv + (size_t)l*3*D_*D_, qkv_b + l*3*D_, vrb, nullptr, qrb, krb, rtab, 3*D_, D_);
    attn_k<<<dim3(L_/32, B_*H_), 256, 0, stream>>>(qrb, krb, vrb, bw, ybf, l);
    gemm_bt<1,64,2,0><<<dim3(D_/128, M_/64, 2), 256, 0, stream>>>(
        ybf, nullptr, wout + (size_t)l*D_*D_, out_b + l*D_, nullptr, s, nullptr, nullptr, nullptr, D_, D_);
    gemm_bt<2,128,1,1><<<dim3(MLP_/128, M_/128), 256, 0, stream>>>(
        nullptr, s, wfc1 + (size_t)l*MLP_*D_, fc1_b + l*MLP_, gbf, nullptr, nullptr, nullptr, nullptr, MLP_, D_);
    gemm_bt<3,64,4,0><<<dim3(D_/128, M_/64, 4), 256, 0, stream>>>(
        gbf, nullptr, wfc2 + (size_t)l*D_*MLP_, fc2_b + l*D_, nullptr, s, nullptr, nullptr, nullptr, D_, MLP_);
  }
}

// Round 5
// 1002.040 us; speedup vs baseline: 1.2198x; 1.2198x over previous
//
#include <hip/hip_runtime.h>

#define B_    2
#define L_    1024
#define D_    768
#define H_    12
#define DH_   64
#define DP_   32
#define MLP_  3072
#define NL_   4
#define WIN_  128
#define W2_   257            // window columns (rel = j-i+128 in [0,256])
#define M_    (B_*L_)        // 2048 rows

typedef __attribute__((ext_vector_type(8))) short bf16x8;
typedef __attribute__((ext_vector_type(4))) float f32x4;

__device__ __forceinline__ unsigned short f2bf(float x){
  unsigned int u = __float_as_uint(x);
  u += 0x7fffu + ((u >> 16) & 1u);   // RNE; inputs finite
  return (unsigned short)(u >> 16);
}

__device__ __forceinline__ void gl_lds16(const void* g, void* l){
  __builtin_amdgcn_global_load_lds((__attribute__((address_space(1))) void*)g,
                                   (__attribute__((address_space(3))) void*)l, 16, 0, 0);
}

// ---------------- fused prologue: pair-bias + rope table + all weight cvt ----------------
// block ranges: [0,2056) pair_bias | [2056,2184) rope table | [2184,29832) weight cvt
#define PB_BLKS_   2056
#define RT_BLKS_   128
#define CVT_Q0_    1769472    // qkv_w quads (4*2304*768/4)
#define CVT_Q1_    2359296    // + out_w quads
#define CVT_Q2_    4718592    // + fc1_w quads
#define CVT_Q3_    7077888    // + fc2_w quads (total)
__global__ __launch_bounds__(256) void prologue_k(
    const float* __restrict__ pair, const float* __restrict__ ln_g,
    const float* __restrict__ ln_b, const float* __restrict__ pb_w,
    const float* __restrict__ pb_b, float* __restrict__ bias,
    float2* __restrict__ rtab,
    const float* __restrict__ qkv_w, const float* __restrict__ out_w,
    const float* __restrict__ fc1_w, const float* __restrict__ fc2_w,
    unsigned short* __restrict__ wall){
  __shared__ float gw[NL_][DP_];
  __shared__ float cb[NL_];
  const int bid = blockIdx.x, tid = threadIdx.x;
  if (bid < PB_BLKS_){
    // ---- pair bias: LN(pair)@pb_w + pb_b for ALL layers, window only ----
    if (tid < NL_*DP_) gw[tid>>5][tid&31] = ln_g[tid]*pb_w[tid];
    if (tid < NL_){
      float c = 0.f;
      for (int d=0; d<DP_; ++d) c += ln_b[tid*DP_+d]*pb_w[tid*DP_+d];
      cb[tid] = c + pb_b[tid];
    }
    __syncthreads();
    int idx = bid*256 + tid;
    if (idx >= B_*L_*W2_) return;
    int rel = idx % W2_;
    int t   = idx / W2_;
    int i   = t & (L_-1);
    int b   = t >> 10;
    int j   = i + rel - WIN_;
    if (j < 0 || j >= L_) return;            // never read by attention
    const float4* p = (const float4*)(pair + ((size_t)(b*L_ + i)*L_ + j)*DP_);
    float4 x[8];
    #pragma unroll
    for (int q=0;q<8;++q) x[q] = p[q];
    float s=0.f, ss=0.f;
    #pragma unroll
    for (int q=0;q<8;++q){
      s  += x[q].x + x[q].y + x[q].z + x[q].w;
      ss += x[q].x*x[q].x + x[q].y*x[q].y + x[q].z*x[q].z + x[q].w*x[q].w;
    }
    float m  = s * (1.0f/DP_);
    float rs = rsqrtf(ss*(1.0f/DP_) - m*m + 1e-5f);
    #pragma unroll
    for (int l=0;l<NL_;++l){
      float acc = 0.f;
      #pragma unroll
      for (int q=0;q<8;++q){
        acc += (x[q].x-m)*gw[l][4*q+0] + (x[q].y-m)*gw[l][4*q+1]
             + (x[q].z-m)*gw[l][4*q+2] + (x[q].w-m)*gw[l][4*q+3];
      }
      bias[(((size_t)l*B_ + b)*L_ + i)*W2_ + rel] = acc*rs + cb[l];
    }
  } else if (bid < PB_BLKS_ + RT_BLKS_){
    // ---- rope cos/sin table [L][32] ----
    int idx = (bid - PB_BLKS_)*256 + tid;
    int t = idx & 31, i = idx >> 5;
    float invf = expf(-(float)t * 0.28782313662425572f);   // ln(10000)/32
    float ang = (float)i * invf;
    float sn, cs;
    sincosf(ang, &sn, &cs);
    rtab[idx] = make_float2(cs, sn);
  } else {
    // ---- f32 -> bf16 weight conversion (all four weight tensors) ----
    size_t q = (size_t)(bid - PB_BLKS_ - RT_BLKS_)*256 + tid;
    const float* src; unsigned short* dst; size_t ql;
    if (q < CVT_Q0_)      { ql = q;            src = qkv_w; dst = wall; }
    else if (q < CVT_Q1_) { ql = q - CVT_Q0_;  src = out_w; dst = wall + (size_t)CVT_Q0_*4; }
    else if (q < CVT_Q2_) { ql = q - CVT_Q1_;  src = fc1_w; dst = wall + (size_t)CVT_Q1_*4; }
    else                  { ql = q - CVT_Q2_;  src = fc2_w; dst = wall + (size_t)CVT_Q2_*4; }
    float4 v = ((const float4*)src)[ql];
    ushort4 o;
    o.x = f2bf(v.x); o.y = f2bf(v.y); o.z = f2bf(v.z); o.w = f2bf(v.w);
    ((ushort4*)dst)[ql] = o;
  }
}

// ---------------- rmsnorm: s[M,768] f32 -> h bf16 ----------------
__global__ __launch_bounds__(256) void rmsnorm_k(const float* __restrict__ s,
                                                 unsigned short* __restrict__ h){
  int row = blockIdx.x, tid = threadIdx.x;
  const float* x = s + (size_t)row*D_;
  float v0 = x[tid], v1 = x[tid+256], v2 = x[tid+512];
  float ss = v0*v0 + v1*v1 + v2*v2;
  #pragma unroll
  for (int m=1; m<64; m<<=1) ss += __shfl_xor(ss, m, 64);
  __shared__ float wsum[4];
  __shared__ float rbuf;
  if ((tid & 63) == 0) wsum[tid>>6] = ss;
  __syncthreads();
  if (tid == 0) rbuf = rsqrtf((wsum[0]+wsum[1]+wsum[2]+wsum[3])*(1.0f/D_) + 1.1920929e-07f);
  __syncthreads();
  float r = rbuf;
  unsigned short* o = h + (size_t)row*D_;
  o[tid]     = f2bf(v0*r);
  o[tid+256] = f2bf(v1*r);
  o[tid+512] = f2bf(v2*r);
}

// ---------------- bf16 GEMM: C[M,N] = A[M,K] @ W[N,K]^T + bias, fused epilogues ----
// MODE 0: qkv — q,k get RoPE applied in-register (partner col+32 is acc[mi][ni+2]),
//         written bf16 to outq/outk in [bh][i][64]; v cols -> outb bf16 [bh][j][64].
// MODE 1: resid += C          (attn out proj)
// MODE 2: outb = bf16(gelu(C))(fc1)
// MODE 3: resid += C          (fc2)
// TM: 128 or 64 (M rows per block). SPLIT: split-K factor (atomicAdd epilogue if >1).
template<int MODE, int TM, int SPLIT>
__global__ __launch_bounds__(256) void gemm_bt(const unsigned short* __restrict__ A,
    const unsigned short* __restrict__ W, const float* __restrict__ bias,
    unsigned short* __restrict__ outb, float* __restrict__ resid,
    unsigned short* __restrict__ outq, unsigned short* __restrict__ outk,
    const float2* __restrict__ rtab, int N, int K){
  constexpr int MI = TM/32;
  __shared__ __align__(16) short sm[2][(TM+128)*32];
  const int tid  = threadIdx.x;
  const int wave = tid >> 6, lane = tid & 63;
  const int m0 = blockIdx.y*TM, n0 = blockIdx.x << 7;
  const int KB = K / SPLIT;
  const int kbase = blockIdx.z * KB;
  const int wm = (wave >> 1)*(TM/2), wn = (wave & 1) << 6;
  const int lrow = lane & 15, ko = (lane >> 4) << 3;
  f32x4 acc[MI][4] = {};
  const unsigned short* Ag = A + (size_t)(m0 + (tid>>2))*K + kbase + ((tid&3)<<3);
  const unsigned short* Wg = W + (size_t)(n0 + (tid>>2))*K + kbase + ((tid&3)<<3);
  const size_t hstep = (size_t)64*K;
  const int nk = KB >> 5;
  {  // prologue stage into buf 0
    short* As = sm[0]; short* Bs = sm[0] + TM*32;
    gl_lds16(Ag, &As[tid*8]);
    if (TM == 128) gl_lds16(Ag + hstep, &As[(tid+256)*8]);
    gl_lds16(Wg, &Bs[tid*8]);
    gl_lds16(Wg + hstep, &Bs[(tid+256)*8]);
  }
  for (int it = 0; it < nk; ++it){
    __syncthreads();                       // drains vmcnt -> buf (it&1) ready
    if (it + 1 < nk){                      // async-prefetch next tile, overlaps MFMA below
      short* As = sm[(it&1)^1]; short* Bs = As + TM*32;
      const int kt = (it+1) << 5;
      gl_lds16(Ag + kt, &As[tid*8]);
      if (TM == 128) gl_lds16(Ag + hstep + kt, &As[(tid+256)*8]);
      gl_lds16(Wg + kt, &Bs[tid*8]);
      gl_lds16(Wg + hstep + kt, &Bs[(tid+256)*8]);
    }
    const short* As = sm[it&1]; const short* Bs = As + TM*32;
    bf16x8 af[MI], bv[4];
    #pragma unroll
    for (int i=0;i<MI;++i) af[i] = *(const bf16x8*)&As[((wm + i*16 + lrow) << 5) + ko];
    #pragma unroll
    for (int i=0;i<4;++i)  bv[i] = *(const bf16x8*)&Bs[((wn + i*16 + lrow) << 5) + ko];
    #pragma unroll
    for (int mi=0;mi<MI;++mi)
      #pragma unroll
      for (int ni=0;ni<4;++ni)
        acc[mi][ni] = __builtin_amdgcn_mfma_f32_16x16x32_bf16(af[mi], bv[ni], acc[mi][ni], 0, 0, 0);
  }
  if (MODE == 0){
    // rope-fused epilogue: process (ni, ni+2) pairs = (d, d+32) of one head
    #pragma unroll
    for (int ni=0; ni<2; ++ni){
      const int col0 = n0 + wn + ni*16 + lrow;       // d = d0 in [0,32)
      const int d0 = ni*16 + lrow;
      const float b0 = bias[col0], b2 = bias[col0 + 32];
      #pragma unroll
      for (int mi=0; mi<MI; ++mi){
        const int rw = m0 + wm + mi*16 + ((lane >> 4) << 2);
        #pragma unroll
        for (int r=0; r<4; ++r){
          const int rowg = rw + r;
          const int bI = rowg >> 10, iI = rowg & (L_-1);
          const float v0 = acc[mi][ni][r]   + b0;
          const float v2 = acc[mi][ni+2][r] + b2;
          if (col0 < 2*D_){
            const bool isq = (col0 < D_);
            const int  h   = (isq ? col0 : col0 - D_) >> 6;
            const float2 cssn = rtab[iI*32 + d0];
            const float o0 = v0*cssn.x - v2*cssn.y;   // d<32: q*c - q[d+32]*s
            const float o2 = v2*cssn.x + v0*cssn.y;   // d>=32: q*c + q[d-32]*s
            unsigned short* dst = (isq ? outq : outk)
                + ((((size_t)(bI*H_ + h)) << 10 | iI) << 6);
            dst[d0]      = f2bf(o0);
            dst[d0 + 32] = f2bf(o2);
          } else {
            const int h = (col0 - 2*D_) >> 6;
            unsigned short* dst = outb + ((((size_t)(bI*H_ + h)) << 10 | iI) << 6);
            dst[d0]      = f2bf(v0);
            dst[d0 + 32] = f2bf(v2);
          }
        }
      }
    }
  } else {
    #pragma unroll
    for (int ni=0;ni<4;++ni){
      const int col = n0 + wn + ni*16 + lrow;
      const float bb = (SPLIT == 1 || blockIdx.z == 0) ? bias[col] : 0.f;
      #pragma unroll
      for (int mi=0;mi<MI;++mi){
        const int rw = m0 + wm + mi*16 + ((lane >> 4) << 2);
        #pragma unroll
        for (int r=0;r<4;++r){
          float v = acc[mi][ni][r] + bb;
          if (MODE == 2){
            float g = 0.5f * v * (1.0f + erff(v * 0.70710678118654752f));
            outb[(size_t)(rw + r)*N + col] = f2bf(g);
          } else {
            if (SPLIT == 1) resid[(size_t)(rw + r)*D_ + col] += v;
            else            atomicAdd(&resid[(size_t)(rw + r)*D_ + col], v);
          }
        }
      }
    }
  }
}

// ---------------- windowed MFMA attention, 32-query tiles ----------------
// Per block: one (bh, 32-query tile). K-strip of 288 keys staged bf16 in LDS
// (precomputed bf16 K, no conversion), QK^T and PV via 16x16x32 bf16 MFMA.
// V (precomputed bf16) reuses the K buffer after softmax.
__global__ __launch_bounds__(256) void attn_k(const unsigned short* __restrict__ qr,
    const unsigned short* __restrict__ kr, const unsigned short* __restrict__ vr,
    const float* __restrict__ bias, unsigned short* __restrict__ ybf, int layer){
  __shared__ __align__(16) short kb[288*72];   // K then V, row stride 72 (+8 pad) = 41472 B
  __shared__ __align__(16) float sc[32*304];   // scores f32; probs bf16 alias below
  short* ps = (short*)sc;                      // [32][296] bf16 (stride 296: conflict-free b128)
  const int tid  = threadIdx.x;
  const int wave = tid >> 6, lane = tid & 63;
  const int quad = lane >> 4, lrow = lane & 15;
  const int bh = blockIdx.y, b = bh / H_, h = bh - b*H_;
  const int i0 = blockIdx.x * 32, jb = i0 - WIN_;

  // Q fragments for both 16-row m-tiles: A[m=lrow][k=quad*8+j], two K=32 halves
  bf16x8 qf[2][2];
  #pragma unroll
  for (int mt=0; mt<2; ++mt){
    const unsigned short* qrow = qr + (((size_t)bh*L_ + i0 + mt*16 + lrow) << 6) + quad*8;
    qf[mt][0] = *(const bf16x8*)qrow;
    qf[mt][1] = *(const bf16x8*)(qrow + 32);
  }
  // stage K strip (288 rows x 64 bf16), zero-filled outside [0,L)
  {
    const int r0 = tid >> 3, seg = tid & 7;
    #pragma unroll
    for (int p=0; p<9; ++p){
      const int r = r0 + p*32;
      const int jg = jb + r;
      bf16x8 z;
      #pragma unroll
      for (int q=0;q<8;++q) z[q] = 0;
      if ((unsigned)jg < L_) z = *(const bf16x8*)(kr + (((size_t)bh*L_ + jg) << 6) + seg*8);
      *(bf16x8*)&kb[r*72 + seg*8] = z;
    }
  }
  __syncthreads();
  // QK^T: 18 key-chunks of 16, round-robin over waves; each wave does both m-tiles
  for (int c = wave; c < 18; c += 4){
    const int krow = c*16 + lrow;
    const bf16x8 kf0 = *(const bf16x8*)&kb[krow*72 + quad*8];
    const bf16x8 kf1 = *(const bf16x8*)&kb[krow*72 + 32 + quad*8];
    const int jj = c*16 + lrow, jg = jb + jj;
    #pragma unroll
    for (int mt=0; mt<2; ++mt){
      f32x4 cc = {0.f,0.f,0.f,0.f};
      cc = __builtin_amdgcn_mfma_f32_16x16x32_bf16(qf[mt][0], kf0, cc, 0, 0, 0);
      cc = __builtin_amdgcn_mfma_f32_16x16x32_bf16(qf[mt][1], kf1, cc, 0, 0, 0);
      #pragma unroll
      for (int r=0;r<4;++r){
        const int row = mt*16 + quad*4 + r;
        const int rel = jj - row;             // j - i + 128
        float v = -1e30f;
        if (rel >= 0 && rel <= 256 && (unsigned)jg < L_)
          v = cc[r]*0.125f + bias[(((size_t)(layer*B_ + b))*L_ + i0 + row)*W2_ + rel];
        sc[row*304 + jj] = v;
      }
    }
  }
  __syncthreads();
  // softmax: thread group of 16 handles rows qq and qq+16
  const int qq = tid >> 4, tj = tid & 15;
  float ev[2][18];
  #pragma unroll
  for (int g=0; g<2; ++g)
    #pragma unroll
    for (int c=0;c<18;++c) ev[g][c] = sc[(qq + g*16)*304 + c*16 + tj];
  __syncthreads();                 // all sc reads done before ps alias-writes
  #pragma unroll
  for (int g=0; g<2; ++g){
    float mx = -3.0e38f;
    #pragma unroll
    for (int c=0;c<18;++c) mx = fmaxf(mx, ev[g][c]);
    #pragma unroll
    for (int m=1; m<16; m<<=1) mx = fmaxf(mx, __shfl_xor(mx, m, 16));
    float sm = 0.f;
    #pragma unroll
    for (int c=0;c<18;++c){ float e = __expf(ev[g][c] - mx); ev[g][c] = e; sm += e; }
    #pragma unroll
    for (int m=1; m<16; m<<=1) sm += __shfl_xor(sm, m, 16);
    const float inv = 1.0f / sm;
    #pragma unroll
    for (int c=0;c<18;++c) ps[(qq + g*16)*296 + c*16 + tj] = (short)f2bf(ev[g][c]*inv);
  }
  // stage V into kb (zero-fill: ps~0 rows must not meet inf/NaN)
  {
    const int r0 = tid >> 3, seg = tid & 7;
    #pragma unroll
    for (int p=0; p<9; ++p){
      const int r = r0 + p*32;
      const int jg = jb + r;
      bf16x8 z;
      #pragma unroll
      for (int q=0;q<8;++q) z[q] = 0;
      if ((unsigned)jg < L_) z = *(const bf16x8*)(vr + (((size_t)bh*L_ + jg) << 6) + seg*8);
      *(bf16x8*)&kb[r*72 + seg*8] = z;
    }
  }
  __syncthreads();
  // PV: O[32][64] = P[32x288] @ V[288x64]; wave owns d-tile [wave*16, wave*16+16)
  f32x4 o0 = {0.f,0.f,0.f,0.f}, o1 = {0.f,0.f,0.f,0.f};
  for (int kc=0; kc<9; ++kc){
    bf16x8 bf;
    #pragma unroll
    for (int j=0;j<8;++j) bf[j] = kb[(kc*32 + quad*8 + j)*72 + wave*16 + lrow];
    const bf16x8 a0 = *(const bf16x8*)&ps[lrow*296 + kc*32 + quad*8];
    const bf16x8 a1 = *(const bf16x8*)&ps[(16 + lrow)*296 + kc*32 + quad*8];
    o0 = __builtin_amdgcn_mfma_f32_16x16x32_bf16(a0, bf, o0, 0, 0, 0);
    o1 = __builtin_amdgcn_mfma_f32_16x16x32_bf16(a1, bf, o1, 0, 0, 0);
  }
  #pragma unroll
  for (int r=0;r<4;++r){
    const int row = quad*4 + r;
    ybf[((size_t)(b*L_ + i0 + row))*D_ + h*64 + wave*16 + lrow]      = f2bf(o0[r]);
    ybf[((size_t)(b*L_ + i0 + 16 + row))*D_ + h*64 + wave*16 + lrow] = f2bf(o1[r]);
  }
}

extern "C" void kernel_launch(void* const* d_in, const int* in_sizes, int n_in,
                              void* d_out, int out_size, void* d_ws, size_t ws_size,
                              hipStream_t stream){
  (void)in_sizes; (void)n_in; (void)out_size; (void)ws_size;
  const float* s_in  = (const float*)d_in[0];
  const float* pair  = (const float*)d_in[1];
  const float* qkv_w = (const float*)d_in[2];
  const float* qkv_b = (const float*)d_in[3];
  const float* out_w = (const float*)d_in[4];
  const float* out_b = (const float*)d_in[5];
  const float* fc1_w = (const float*)d_in[6];
  const float* fc1_b = (const float*)d_in[7];
  const float* fc2_w = (const float*)d_in[8];
  const float* fc2_b = (const float*)d_in[9];
  const float* ln_g  = (const float*)d_in[10];
  const float* ln_b  = (const float*)d_in[11];
  const float* pb_w  = (const float*)d_in[12];
  const float* pb_b  = (const float*)d_in[13];
  float* s = (float*)d_out;                    // residual stream lives in d_out

  char* ws = (char*)d_ws;
  size_t off = 0;
  auto take = [&](size_t bytes)->char*{
    char* p = ws + off; off += (bytes + 255) & ~(size_t)255; return p;
  };
  // NOTE: wqkv..wfc2 must stay contiguous (prologue_k writes via one base ptr);
  // all four sizes are exact multiples of 256 B.
  unsigned short* wqkv = (unsigned short*)take((size_t)NL_*3*D_*D_*2);
  unsigned short* wout = (unsigned short*)take((size_t)NL_*D_*D_*2);
  unsigned short* wfc1 = (unsigned short*)take((size_t)NL_*MLP_*D_*2);
  unsigned short* wfc2 = (unsigned short*)take((size_t)NL_*D_*MLP_*2);
  float*          bw   = (float*)take((size_t)NL_*B_*L_*W2_*4);
  unsigned short* hbf  = (unsigned short*)take((size_t)M_*D_*2);
  unsigned short* qrb  = (unsigned short*)take((size_t)B_*H_*L_*DH_*2);
  unsigned short* krb  = (unsigned short*)take((size_t)B_*H_*L_*DH_*2);
  unsigned short* vrb  = (unsigned short*)take((size_t)B_*H_*L_*DH_*2);
  unsigned short* ybf  = (unsigned short*)take((size_t)M_*D_*2);
  unsigned short* gbf  = (unsigned short*)take((size_t)M_*MLP_*2);
  float2*         rtab = (float2*)take((size_t)L_*32*sizeof(float2));

  hipMemcpyAsync(s, s_in, (size_t)M_*D_*sizeof(float), hipMemcpyDeviceToDevice, stream);

  prologue_k<<<PB_BLKS_ + RT_BLKS_ + CVT_Q3_/256, 256, 0, stream>>>(
      pair, ln_g, ln_b, pb_w, pb_b, bw, rtab,
      qkv_w, out_w, fc1_w, fc2_w, wqkv);

  for (int l=0; l<NL_; ++l){
    rmsnorm_k<<<M_, 256, 0, stream>>>(s, hbf);
    gemm_bt<0,128,1><<<dim3((3*D_)/128, M_/128), 256, 0, stream>>>(
        hbf, wqkv + (size_t)l*3*D_*D_, qkv_b + l*3*D_, vrb, nullptr, qrb, krb, rtab, 3*D_, D_);
    attn_k<<<dim3(L_/32, B_*H_), 256, 0, stream>>>(qrb, krb, vrb, bw, ybf, l);
    gemm_bt<1,64,2><<<dim3(D_/128, M_/64, 2), 256, 0, stream>>>(
        ybf, wout + (size_t)l*D_*D_, out_b + l*D_, nullptr, s, nullptr, nullptr, nullptr, D_, D_);
    rmsnorm_k<<<M_, 256, 0, stream>>>(s, hbf);
    gemm_bt<2,128,1><<<dim3(MLP_/128, M_/128), 256, 0, stream>>>(
        hbf, wfc1 + (size_t)l*MLP_*D_, fc1_b + l*MLP_, gbf, nullptr, nullptr, nullptr, nullptr, MLP_, D_);
    gemm_bt<3,64,4><<<dim3(D_/128, M_/64, 4), 256, 0, stream>>>(
        gbf, wfc2 + (size_t)l*D_*MLP_, fc2_b + l*D_, nullptr, s, nullptr, nullptr, nullptr, D_, MLP_);
  }
}

// Round 6
// 952.036 us; speedup vs baseline: 1.2838x; 1.0525x over previous
//
#include <hip/hip_runtime.h>

#define B_    2
#define L_    1024
#define D_    768
#define H_    12
#define DH_   64
#define DP_   32
#define MLP_  3072
#define NL_   4
#define WIN_  128
#define W2_   257            // window columns (rel = j-i+128 in [0,256])
#define M_    (B_*L_)        // 2048 rows

typedef __attribute__((ext_vector_type(8))) short bf16x8;
typedef __attribute__((ext_vector_type(4))) float f32x4;

__device__ __forceinline__ unsigned short f2bf(float x){
  unsigned int u = __float_as_uint(x);
  u += 0x7fffu + ((u >> 16) & 1u);   // RNE; inputs finite
  return (unsigned short)(u >> 16);
}

__device__ __forceinline__ void gl_lds16(const void* g, void* l){
  __builtin_amdgcn_global_load_lds((__attribute__((address_space(1))) void*)g,
                                   (__attribute__((address_space(3))) void*)l, 16, 0, 0);
}

// ---------------- fused prologue: pair-bias + rope table + all weight cvt ----------------
// block ranges: [0,2056) pair_bias | [2056,2184) rope table | [2184,29832) weight cvt
#define PB_BLKS_   2056
#define RT_BLKS_   128
#define CVT_Q0_    1769472    // qkv_w quads (4*2304*768/4)
#define CVT_Q1_    2359296    // + out_w quads
#define CVT_Q2_    4718592    // + fc1_w quads
#define CVT_Q3_    7077888    // + fc2_w quads (total)
__global__ __launch_bounds__(256) void prologue_k(
    const float* __restrict__ pair, const float* __restrict__ ln_g,
    const float* __restrict__ ln_b, const float* __restrict__ pb_w,
    const float* __restrict__ pb_b, float* __restrict__ bias,
    float2* __restrict__ rtab,
    const float* __restrict__ qkv_w, const float* __restrict__ out_w,
    const float* __restrict__ fc1_w, const float* __restrict__ fc2_w,
    unsigned short* __restrict__ wall){
  __shared__ float gw[NL_][DP_];
  __shared__ float cb[NL_];
  const int bid = blockIdx.x, tid = threadIdx.x;
  if (bid < PB_BLKS_){
    // ---- pair bias: LN(pair)@pb_w + pb_b for ALL layers, window only ----
    if (tid < NL_*DP_) gw[tid>>5][tid&31] = ln_g[tid]*pb_w[tid];
    if (tid < NL_){
      float c = 0.f;
      for (int d=0; d<DP_; ++d) c += ln_b[tid*DP_+d]*pb_w[tid*DP_+d];
      cb[tid] = c + pb_b[tid];
    }
    __syncthreads();
    int idx = bid*256 + tid;
    if (idx >= B_*L_*W2_) return;
    int rel = idx % W2_;
    int t   = idx / W2_;
    int i   = t & (L_-1);
    int b   = t >> 10;
    int j   = i + rel - WIN_;
    if (j < 0 || j >= L_) return;            // never read by attention
    const float4* p = (const float4*)(pair + ((size_t)(b*L_ + i)*L_ + j)*DP_);
    float4 x[8];
    #pragma unroll
    for (int q=0;q<8;++q) x[q] = p[q];
    float s=0.f, ss=0.f;
    #pragma unroll
    for (int q=0;q<8;++q){
      s  += x[q].x + x[q].y + x[q].z + x[q].w;
      ss += x[q].x*x[q].x + x[q].y*x[q].y + x[q].z*x[q].z + x[q].w*x[q].w;
    }
    float m  = s * (1.0f/DP_);
    float rs = rsqrtf(ss*(1.0f/DP_) - m*m + 1e-5f);
    #pragma unroll
    for (int l=0;l<NL_;++l){
      float acc = 0.f;
      #pragma unroll
      for (int q=0;q<8;++q){
        acc += (x[q].x-m)*gw[l][4*q+0] + (x[q].y-m)*gw[l][4*q+1]
             + (x[q].z-m)*gw[l][4*q+2] + (x[q].w-m)*gw[l][4*q+3];
      }
      bias[(((size_t)l*B_ + b)*L_ + i)*W2_ + rel] = acc*rs + cb[l];
    }
  } else if (bid < PB_BLKS_ + RT_BLKS_){
    // ---- rope cos/sin table [L][32] ----
    int idx = (bid - PB_BLKS_)*256 + tid;
    int t = idx & 31, i = idx >> 5;
    float invf = expf(-(float)t * 0.28782313662425572f);   // ln(10000)/32
    float ang = (float)i * invf;
    float sn, cs;
    sincosf(ang, &sn, &cs);
    rtab[idx] = make_float2(cs, sn);
  } else {
    // ---- f32 -> bf16 weight conversion (all four weight tensors) ----
    size_t q = (size_t)(bid - PB_BLKS_ - RT_BLKS_)*256 + tid;
    const float* src; unsigned short* dst; size_t ql;
    if (q < CVT_Q0_)      { ql = q;            src = qkv_w; dst = wall; }
    else if (q < CVT_Q1_) { ql = q - CVT_Q0_;  src = out_w; dst = wall + (size_t)CVT_Q0_*4; }
    else if (q < CVT_Q2_) { ql = q - CVT_Q1_;  src = fc1_w; dst = wall + (size_t)CVT_Q1_*4; }
    else                  { ql = q - CVT_Q2_;  src = fc2_w; dst = wall + (size_t)CVT_Q2_*4; }
    float4 v = ((const float4*)src)[ql];
    ushort4 o;
    o.x = f2bf(v.x); o.y = f2bf(v.y); o.z = f2bf(v.z); o.w = f2bf(v.w);
    ((ushort4*)dst)[ql] = o;
  }
}

// ---------------- rmsnorm (+ optional split-K partial fold): s[M,768] f32 -> h bf16 ----
// NS>0: s += sum_z P[z][row][:], written back to s, then rmsnorm of the new s.
template<int NS>
__global__ __launch_bounds__(256) void rmsnorm_k(float* __restrict__ s,
                                                 const float* __restrict__ P,
                                                 unsigned short* __restrict__ h){
  int row = blockIdx.x, tid = threadIdx.x;
  float* x = s + (size_t)row*D_;
  float v0 = x[tid], v1 = x[tid+256], v2 = x[tid+512];
  if constexpr (NS > 0){
    #pragma unroll
    for (int z=0; z<NS; ++z){
      const float* p = P + ((size_t)z*M_ + row)*D_;
      v0 += p[tid]; v1 += p[tid+256]; v2 += p[tid+512];
    }
    x[tid] = v0; x[tid+256] = v1; x[tid+512] = v2;
  }
  float ss = v0*v0 + v1*v1 + v2*v2;
  #pragma unroll
  for (int m=1; m<64; m<<=1) ss += __shfl_xor(ss, m, 64);
  __shared__ float wsum[4];
  __shared__ float rbuf;
  if ((tid & 63) == 0) wsum[tid>>6] = ss;
  __syncthreads();
  if (tid == 0) rbuf = rsqrtf((wsum[0]+wsum[1]+wsum[2]+wsum[3])*(1.0f/D_) + 1.1920929e-07f);
  __syncthreads();
  float r = rbuf;
  unsigned short* o = h + (size_t)row*D_;
  o[tid]     = f2bf(v0*r);
  o[tid+256] = f2bf(v1*r);
  o[tid+512] = f2bf(v2*r);
}

// ---------------- final split-K reduce: s += sum of 4 partials ----------------
__global__ __launch_bounds__(256) void reduce_k(float* __restrict__ s,
                                                const float* __restrict__ P){
  int idx = blockIdx.x*256 + threadIdx.x;          // over M*D/4 float4s
  float4 v = ((float4*)s)[idx];
  #pragma unroll
  for (int z=0; z<4; ++z){
    float4 p = ((const float4*)(P + (size_t)z*M_*D_))[idx];
    v.x += p.x; v.y += p.y; v.z += p.z; v.w += p.w;
  }
  ((float4*)s)[idx] = v;
}

// ---------------- bf16 GEMM: C[M,N] = A[M,K] @ W[N,K]^T + bias, fused epilogues ----
// MODE 0: qkv — q,k get RoPE applied in-register (partner col+32 is acc[mi][ni+2]),
//         written bf16 to outq/outk in [bh][i][64]; v cols -> outb bf16 [bh][j][64].
// MODE 1: attn out proj — SPLIT=1: resid += C; SPLIT>1: partials[z] = C (no atomics)
// MODE 2: outb = bf16(gelu(C))(fc1)
// MODE 3: fc2 — same as MODE 1
// TM: 128 or 64 (M rows per block). SPLIT: split-K factor (partial-buffer epilogue if >1).
template<int MODE, int TM, int SPLIT>
__global__ __launch_bounds__(256) void gemm_bt(const unsigned short* __restrict__ A,
    const unsigned short* __restrict__ W, const float* __restrict__ bias,
    unsigned short* __restrict__ outb, float* __restrict__ resid,
    unsigned short* __restrict__ outq, unsigned short* __restrict__ outk,
    const float2* __restrict__ rtab, int N, int K){
  constexpr int MI = TM/32;
  __shared__ __align__(16) short sm[2][(TM+128)*32];
  const int tid  = threadIdx.x;
  const int wave = tid >> 6, lane = tid & 63;
  const int m0 = blockIdx.y*TM, n0 = blockIdx.x << 7;
  const int KB = K / SPLIT;
  const int kbase = blockIdx.z * KB;
  const int wm = (wave >> 1)*(TM/2), wn = (wave & 1) << 6;
  const int lrow = lane & 15, ko = (lane >> 4) << 3;
  f32x4 acc[MI][4] = {};
  const unsigned short* Ag = A + (size_t)(m0 + (tid>>2))*K + kbase + ((tid&3)<<3);
  const unsigned short* Wg = W + (size_t)(n0 + (tid>>2))*K + kbase + ((tid&3)<<3);
  const size_t hstep = (size_t)64*K;
  const int nk = KB >> 5;
  {  // prologue stage into buf 0
    short* As = sm[0]; short* Bs = sm[0] + TM*32;
    gl_lds16(Ag, &As[tid*8]);
    if (TM == 128) gl_lds16(Ag + hstep, &As[(tid+256)*8]);
    gl_lds16(Wg, &Bs[tid*8]);
    gl_lds16(Wg + hstep, &Bs[(tid+256)*8]);
  }
  for (int it = 0; it < nk; ++it){
    __syncthreads();                       // drains vmcnt -> buf (it&1) ready
    if (it + 1 < nk){                      // async-prefetch next tile, overlaps MFMA below
      short* As = sm[(it&1)^1]; short* Bs = As + TM*32;
      const int kt = (it+1) << 5;
      gl_lds16(Ag + kt, &As[tid*8]);
      if (TM == 128) gl_lds16(Ag + hstep + kt, &As[(tid+256)*8]);
      gl_lds16(Wg + kt, &Bs[tid*8]);
      gl_lds16(Wg + hstep + kt, &Bs[(tid+256)*8]);
    }
    const short* As = sm[it&1]; const short* Bs = As + TM*32;
    bf16x8 af[MI], bv[4];
    #pragma unroll
    for (int i=0;i<MI;++i) af[i] = *(const bf16x8*)&As[((wm + i*16 + lrow) << 5) + ko];
    #pragma unroll
    for (int i=0;i<4;++i)  bv[i] = *(const bf16x8*)&Bs[((wn + i*16 + lrow) << 5) + ko];
    #pragma unroll
    for (int mi=0;mi<MI;++mi)
      #pragma unroll
      for (int ni=0;ni<4;++ni)
        acc[mi][ni] = __builtin_amdgcn_mfma_f32_16x16x32_bf16(af[mi], bv[ni], acc[mi][ni], 0, 0, 0);
  }
  if (MODE == 0){
    // rope-fused epilogue: process (ni, ni+2) pairs = (d, d+32) of one head
    #pragma unroll
    for (int ni=0; ni<2; ++ni){
      const int col0 = n0 + wn + ni*16 + lrow;       // d = d0 in [0,32)
      const int d0 = ni*16 + lrow;
      const float b0 = bias[col0], b2 = bias[col0 + 32];
      #pragma unroll
      for (int mi=0; mi<MI; ++mi){
        const int rw = m0 + wm + mi*16 + ((lane >> 4) << 2);
        #pragma unroll
        for (int r=0; r<4; ++r){
          const int rowg = rw + r;
          const int bI = rowg >> 10, iI = rowg & (L_-1);
          const float v0 = acc[mi][ni][r]   + b0;
          const float v2 = acc[mi][ni+2][r] + b2;
          if (col0 < 2*D_){
            const bool isq = (col0 < D_);
            const int  h   = (isq ? col0 : col0 - D_) >> 6;
            const float2 cssn = rtab[iI*32 + d0];
            const float o0 = v0*cssn.x - v2*cssn.y;   // d<32: q*c - q[d+32]*s
            const float o2 = v2*cssn.x + v0*cssn.y;   // d>=32: q*c + q[d-32]*s
            unsigned short* dst = (isq ? outq : outk)
                + ((((size_t)(bI*H_ + h)) << 10 | iI) << 6);
            dst[d0]      = f2bf(o0);
            dst[d0 + 32] = f2bf(o2);
          } else {
            const int h = (col0 - 2*D_) >> 6;
            unsigned short* dst = outb + ((((size_t)(bI*H_ + h)) << 10 | iI) << 6);
            dst[d0]      = f2bf(v0);
            dst[d0 + 32] = f2bf(v2);
          }
        }
      }
    }
  } else {
    #pragma unroll
    for (int ni=0;ni<4;++ni){
      const int col = n0 + wn + ni*16 + lrow;
      const float bb = (SPLIT == 1 || blockIdx.z == 0) ? bias[col] : 0.f;
      #pragma unroll
      for (int mi=0;mi<MI;++mi){
        const int rw = m0 + wm + mi*16 + ((lane >> 4) << 2);
        #pragma unroll
        for (int r=0;r<4;++r){
          float v = acc[mi][ni][r] + bb;
          if (MODE == 2){
            float g = 0.5f * v * (1.0f + erff(v * 0.70710678118654752f));
            outb[(size_t)(rw + r)*N + col] = f2bf(g);
          } else {
            if (SPLIT == 1) resid[(size_t)(rw + r)*D_ + col] += v;
            else            resid[((size_t)blockIdx.z*M_ + (rw + r))*D_ + col] = v;
          }
        }
      }
    }
  }
}

// ---------------- windowed MFMA attention, 32-query tiles ----------------
// Per block: one (bh, 32-query tile). K-strip of 288 keys staged bf16 in LDS
// (precomputed bf16 K, no conversion), QK^T and PV via 16x16x32 bf16 MFMA.
// V (precomputed bf16) reuses the K buffer after softmax.
__global__ __launch_bounds__(256) void attn_k(const unsigned short* __restrict__ qr,
    const unsigned short* __restrict__ kr, const unsigned short* __restrict__ vr,
    const float* __restrict__ bias, unsigned short* __restrict__ ybf, int layer){
  __shared__ __align__(16) short kb[288*72];   // K then V, row stride 72 (+8 pad) = 41472 B
  __shared__ __align__(16) float sc[32*304];   // scores f32; probs bf16 alias below
  short* ps = (short*)sc;                      // [32][296] bf16 (stride 296: conflict-free b128)
  const int tid  = threadIdx.x;
  const int wave = tid >> 6, lane = tid & 63;
  const int quad = lane >> 4, lrow = lane & 15;
  const int bh = blockIdx.y, b = bh / H_, h = bh - b*H_;
  const int i0 = blockIdx.x * 32, jb = i0 - WIN_;

  // Q fragments for both 16-row m-tiles: A[m=lrow][k=quad*8+j], two K=32 halves
  bf16x8 qf[2][2];
  #pragma unroll
  for (int mt=0; mt<2; ++mt){
    const unsigned short* qrow = qr + (((size_t)bh*L_ + i0 + mt*16 + lrow) << 6) + quad*8;
    qf[mt][0] = *(const bf16x8*)qrow;
    qf[mt][1] = *(const bf16x8*)(qrow + 32);
  }
  // stage K strip (288 rows x 64 bf16), zero-filled outside [0,L)
  {
    const int r0 = tid >> 3, seg = tid & 7;
    #pragma unroll
    for (int p=0; p<9; ++p){
      const int r = r0 + p*32;
      const int jg = jb + r;
      bf16x8 z;
      #pragma unroll
      for (int q=0;q<8;++q) z[q] = 0;
      if ((unsigned)jg < L_) z = *(const bf16x8*)(kr + (((size_t)bh*L_ + jg) << 6) + seg*8);
      *(bf16x8*)&kb[r*72 + seg*8] = z;
    }
  }
  __syncthreads();
  // QK^T: 18 key-chunks of 16, round-robin over waves; each wave does both m-tiles
  for (int c = wave; c < 18; c += 4){
    const int krow = c*16 + lrow;
    const bf16x8 kf0 = *(const bf16x8*)&kb[krow*72 + quad*8];
    const bf16x8 kf1 = *(const bf16x8*)&kb[krow*72 + 32 + quad*8];
    const int jj = c*16 + lrow, jg = jb + jj;
    #pragma unroll
    for (int mt=0; mt<2; ++mt){
      f32x4 cc = {0.f,0.f,0.f,0.f};
      cc = __builtin_amdgcn_mfma_f32_16x16x32_bf16(qf[mt][0], kf0, cc, 0, 0, 0);
      cc = __builtin_amdgcn_mfma_f32_16x16x32_bf16(qf[mt][1], kf1, cc, 0, 0, 0);
      #pragma unroll
      for (int r=0;r<4;++r){
        const int row = mt*16 + quad*4 + r;
        const int rel = jj - row;             // j - i + 128
        float v = -1e30f;
        if (rel >= 0 && rel <= 256 && (unsigned)jg < L_)
          v = cc[r]*0.125f + bias[(((size_t)(layer*B_ + b))*L_ + i0 + row)*W2_ + rel];
        sc[row*304 + jj] = v;
      }
    }
  }
  __syncthreads();
  // softmax: thread group of 16 handles rows qq and qq+16
  const int qq = tid >> 4, tj = tid & 15;
  float ev[2][18];
  #pragma unroll
  for (int g=0; g<2; ++g)
    #pragma unroll
    for (int c=0;c<18;++c) ev[g][c] = sc[(qq + g*16)*304 + c*16 + tj];
  __syncthreads();                 // all sc reads done before ps alias-writes
  #pragma unroll
  for (int g=0; g<2; ++g){
    float mx = -3.0e38f;
    #pragma unroll
    for (int c=0;c<18;++c) mx = fmaxf(mx, ev[g][c]);
    #pragma unroll
    for (int m=1; m<16; m<<=1) mx = fmaxf(mx, __shfl_xor(mx, m, 16));
    float sm = 0.f;
    #pragma unroll
    for (int c=0;c<18;++c){ float e = __expf(ev[g][c] - mx); ev[g][c] = e; sm += e; }
    #pragma unroll
    for (int m=1; m<16; m<<=1) sm += __shfl_xor(sm, m, 16);
    const float inv = 1.0f / sm;
    #pragma unroll
    for (int c=0;c<18;++c) ps[(qq + g*16)*296 + c*16 + tj] = (short)f2bf(ev[g][c]*inv);
  }
  // stage V into kb (zero-fill: ps~0 rows must not meet inf/NaN)
  {
    const int r0 = tid >> 3, seg = tid & 7;
    #pragma unroll
    for (int p=0; p<9; ++p){
      const int r = r0 + p*32;
      const int jg = jb + r;
      bf16x8 z;
      #pragma unroll
      for (int q=0;q<8;++q) z[q] = 0;
      if ((unsigned)jg < L_) z = *(const bf16x8*)(vr + (((size_t)bh*L_ + jg) << 6) + seg*8);
      *(bf16x8*)&kb[r*72 + seg*8] = z;
    }
  }
  __syncthreads();
  // PV: O[32][64] = P[32x288] @ V[288x64]; wave owns d-tile [wave*16, wave*16+16)
  f32x4 o0 = {0.f,0.f,0.f,0.f}, o1 = {0.f,0.f,0.f,0.f};
  for (int kc=0; kc<9; ++kc){
    bf16x8 bf;
    #pragma unroll
    for (int j=0;j<8;++j) bf[j] = kb[(kc*32 + quad*8 + j)*72 + wave*16 + lrow];
    const bf16x8 a0 = *(const bf16x8*)&ps[lrow*296 + kc*32 + quad*8];
    const bf16x8 a1 = *(const bf16x8*)&ps[(16 + lrow)*296 + kc*32 + quad*8];
    o0 = __builtin_amdgcn_mfma_f32_16x16x32_bf16(a0, bf, o0, 0, 0, 0);
    o1 = __builtin_amdgcn_mfma_f32_16x16x32_bf16(a1, bf, o1, 0, 0, 0);
  }
  #pragma unroll
  for (int r=0;r<4;++r){
    const int row = quad*4 + r;
    ybf[((size_t)(b*L_ + i0 + row))*D_ + h*64 + wave*16 + lrow]      = f2bf(o0[r]);
    ybf[((size_t)(b*L_ + i0 + 16 + row))*D_ + h*64 + wave*16 + lrow] = f2bf(o1[r]);
  }
}

extern "C" void kernel_launch(void* const* d_in, const int* in_sizes, int n_in,
                              void* d_out, int out_size, void* d_ws, size_t ws_size,
                              hipStream_t stream){
  (void)in_sizes; (void)n_in; (void)out_size; (void)ws_size;
  const float* s_in  = (const float*)d_in[0];
  const float* pair  = (const float*)d_in[1];
  const float* qkv_w = (const float*)d_in[2];
  const float* qkv_b = (const float*)d_in[3];
  const float* out_w = (const float*)d_in[4];
  const float* out_b = (const float*)d_in[5];
  const float* fc1_w = (const float*)d_in[6];
  const float* fc1_b = (const float*)d_in[7];
  const float* fc2_w = (const float*)d_in[8];
  const float* fc2_b = (const float*)d_in[9];
  const float* ln_g  = (const float*)d_in[10];
  const float* ln_b  = (const float*)d_in[11];
  const float* pb_w  = (const float*)d_in[12];
  const float* pb_b  = (const float*)d_in[13];
  float* s = (float*)d_out;                    // residual stream lives in d_out

  char* ws = (char*)d_ws;
  size_t off = 0;
  auto take = [&](size_t bytes)->char*{
    char* p = ws + off; off += (bytes + 255) & ~(size_t)255; return p;
  };
  // NOTE: wqkv..wfc2 must stay contiguous (prologue_k writes via one base ptr);
  // all four sizes are exact multiples of 256 B.
  unsigned short* wqkv = (unsigned short*)take((size_t)NL_*3*D_*D_*2);
  unsigned short* wout = (unsigned short*)take((size_t)NL_*D_*D_*2);
  unsigned short* wfc1 = (unsigned short*)take((size_t)NL_*MLP_*D_*2);
  unsigned short* wfc2 = (unsigned short*)take((size_t)NL_*D_*MLP_*2);
  float*          bw   = (float*)take((size_t)NL_*B_*L_*W2_*4);
  unsigned short* hbf  = (unsigned short*)take((size_t)M_*D_*2);
  unsigned short* qrb  = (unsigned short*)take((size_t)B_*H_*L_*DH_*2);
  unsigned short* krb  = (unsigned short*)take((size_t)B_*H_*L_*DH_*2);
  unsigned short* vrb  = (unsigned short*)take((size_t)B_*H_*L_*DH_*2);
  unsigned short* ybf  = (unsigned short*)take((size_t)M_*D_*2);
  unsigned short* gbf  = (unsigned short*)take((size_t)M_*MLP_*2);
  float2*         rtab = (float2*)take((size_t)L_*32*sizeof(float2));
  float*          pacc = (float*)take((size_t)4*M_*D_*4);   // split-K partials

  hipMemcpyAsync(s, s_in, (size_t)M_*D_*sizeof(float), hipMemcpyDeviceToDevice, stream);

  prologue_k<<<PB_BLKS_ + RT_BLKS_ + CVT_Q3_/256, 256, 0, stream>>>(
      pair, ln_g, ln_b, pb_w, pb_b, bw, rtab,
      qkv_w, out_w, fc1_w, fc2_w, wqkv);

  for (int l=0; l<NL_; ++l){
    if (l == 0) rmsnorm_k<0><<<M_, 256, 0, stream>>>(s, nullptr, hbf);
    else        rmsnorm_k<4><<<M_, 256, 0, stream>>>(s, pacc, hbf);   // fold prev fc2 partials
    gemm_bt<0,128,1><<<dim3((3*D_)/128, M_/128), 256, 0, stream>>>(
        hbf, wqkv + (size_t)l*3*D_*D_, qkv_b + l*3*D_, vrb, nullptr, qrb, krb, rtab, 3*D_, D_);
    attn_k<<<dim3(L_/32, B_*H_), 256, 0, stream>>>(qrb, krb, vrb, bw, ybf, l);
    gemm_bt<1,64,2><<<dim3(D_/128, M_/64, 2), 256, 0, stream>>>(
        ybf, wout + (size_t)l*D_*D_, out_b + l*D_, nullptr, pacc, nullptr, nullptr, nullptr, D_, D_);
    rmsnorm_k<2><<<M_, 256, 0, stream>>>(s, pacc, hbf);               // fold out-proj partials
    gemm_bt<2,128,1><<<dim3(MLP_/128, M_/128), 256, 0, stream>>>(
        hbf, wfc1 + (size_t)l*MLP_*D_, fc1_b + l*MLP_, gbf, nullptr, nullptr, nullptr, nullptr, MLP_, D_);
    gemm_bt<3,64,4><<<dim3(D_/128, M_/64, 4), 256, 0, stream>>>(
        gbf, wfc2 + (size_t)l*D_*MLP_, fc2_b + l*D_, nullptr, pacc, nullptr, nullptr, nullptr, D_, MLP_);
  }
  reduce_k<<<(M_*D_/4)/256, 256, 0, stream>>>(s, pacc);               // fold last fc2 partials
}

// Round 7
// 923.767 us; speedup vs baseline: 1.3231x; 1.0306x over previous
//
#include <hip/hip_runtime.h>

#define B_    2
#define L_    1024
#define D_    768
#define H_    12
#define DH_   64
#define DP_   32
#define MLP_  3072
#define NL_   4
#define WIN_  128
#define W2_   257            // window columns (rel = j-i+128 in [0,256])
#define M_    (B_*L_)        // 2048 rows

typedef __attribute__((ext_vector_type(8))) short bf16x8;
typedef __attribute__((ext_vector_type(4))) float f32x4;

__device__ __forceinline__ unsigned short f2bf(float x){
  unsigned int u = __float_as_uint(x);
  u += 0x7fffu + ((u >> 16) & 1u);   // RNE; inputs finite
  return (unsigned short)(u >> 16);
}

__device__ __forceinline__ void gl_lds16(const void* g, void* l){
  __builtin_amdgcn_global_load_lds((__attribute__((address_space(1))) void*)g,
                                   (__attribute__((address_space(3))) void*)l, 16, 0, 0);
}

// ---------------- fused prologue: pair-bias + rope table + all weight cvt ----------------
// block ranges: [0,2056) pair_bias | [2056,2184) rope table | [2184,29832) weight cvt
#define PB_BLKS_   2056
#define RT_BLKS_   128
#define CVT_Q0_    1769472    // qkv_w quads (4*2304*768/4)
#define CVT_Q1_    2359296    // + out_w quads
#define CVT_Q2_    4718592    // + fc1_w quads
#define CVT_Q3_    7077888    // + fc2_w quads (total)
__global__ __launch_bounds__(256) void prologue_k(
    const float* __restrict__ pair, const float* __restrict__ ln_g,
    const float* __restrict__ ln_b, const float* __restrict__ pb_w,
    const float* __restrict__ pb_b, float* __restrict__ bias,
    float2* __restrict__ rtab,
    const float* __restrict__ qkv_w, const float* __restrict__ out_w,
    const float* __restrict__ fc1_w, const float* __restrict__ fc2_w,
    unsigned short* __restrict__ wall){
  __shared__ float gw[NL_][DP_];
  __shared__ float cb[NL_];
  const int bid = blockIdx.x, tid = threadIdx.x;
  if (bid < PB_BLKS_){
    // ---- pair bias: LN(pair)@pb_w + pb_b for ALL layers, window only ----
    if (tid < NL_*DP_) gw[tid>>5][tid&31] = ln_g[tid]*pb_w[tid];
    if (tid < NL_){
      float c = 0.f;
      for (int d=0; d<DP_; ++d) c += ln_b[tid*DP_+d]*pb_w[tid*DP_+d];
      cb[tid] = c + pb_b[tid];
    }
    __syncthreads();
    int idx = bid*256 + tid;
    if (idx >= B_*L_*W2_) return;
    int rel = idx % W2_;
    int t   = idx / W2_;
    int i   = t & (L_-1);
    int b   = t >> 10;
    int j   = i + rel - WIN_;
    if (j < 0 || j >= L_) return;            // never read by attention
    const float4* p = (const float4*)(pair + ((size_t)(b*L_ + i)*L_ + j)*DP_);
    float4 x[8];
    #pragma unroll
    for (int q=0;q<8;++q) x[q] = p[q];
    float s=0.f, ss=0.f;
    #pragma unroll
    for (int q=0;q<8;++q){
      s  += x[q].x + x[q].y + x[q].z + x[q].w;
      ss += x[q].x*x[q].x + x[q].y*x[q].y + x[q].z*x[q].z + x[q].w*x[q].w;
    }
    float m  = s * (1.0f/DP_);
    float rs = rsqrtf(ss*(1.0f/DP_) - m*m + 1e-5f);
    #pragma unroll
    for (int l=0;l<NL_;++l){
      float acc = 0.f;
      #pragma unroll
      for (int q=0;q<8;++q){
        acc += (x[q].x-m)*gw[l][4*q+0] + (x[q].y-m)*gw[l][4*q+1]
             + (x[q].z-m)*gw[l][4*q+2] + (x[q].w-m)*gw[l][4*q+3];
      }
      bias[(((size_t)l*B_ + b)*L_ + i)*W2_ + rel] = acc*rs + cb[l];
    }
  } else if (bid < PB_BLKS_ + RT_BLKS_){
    // ---- rope cos/sin table [L][32] ----
    int idx = (bid - PB_BLKS_)*256 + tid;
    int t = idx & 31, i = idx >> 5;
    float invf = expf(-(float)t * 0.28782313662425572f);   // ln(10000)/32
    float ang = (float)i * invf;
    float sn, cs;
    sincosf(ang, &sn, &cs);
    rtab[idx] = make_float2(cs, sn);
  } else {
    // ---- f32 -> bf16 weight conversion (all four weight tensors) ----
    size_t q = (size_t)(bid - PB_BLKS_ - RT_BLKS_)*256 + tid;
    const float* src; unsigned short* dst; size_t ql;
    if (q < CVT_Q0_)      { ql = q;            src = qkv_w; dst = wall; }
    else if (q < CVT_Q1_) { ql = q - CVT_Q0_;  src = out_w; dst = wall + (size_t)CVT_Q0_*4; }
    else if (q < CVT_Q2_) { ql = q - CVT_Q1_;  src = fc1_w; dst = wall + (size_t)CVT_Q1_*4; }
    else                  { ql = q - CVT_Q2_;  src = fc2_w; dst = wall + (size_t)CVT_Q2_*4; }
    float4 v = ((const float4*)src)[ql];
    ushort4 o;
    o.x = f2bf(v.x); o.y = f2bf(v.y); o.z = f2bf(v.z); o.w = f2bf(v.w);
    ((ushort4*)dst)[ql] = o;
  }
}

// ---------------- rmsnorm (+ optional split-K partial fold): s[M,768] f32 -> h bf16 ----
// NS>0: s += sum_z P[z][row][:], written back to s, then rmsnorm of the new s.
template<int NS>
__global__ __launch_bounds__(256) void rmsnorm_k(float* __restrict__ s,
                                                 const float* __restrict__ P,
                                                 unsigned short* __restrict__ h){
  int row = blockIdx.x, tid = threadIdx.x;
  float* x = s + (size_t)row*D_;
  float v0 = x[tid], v1 = x[tid+256], v2 = x[tid+512];
  if constexpr (NS > 0){
    #pragma unroll
    for (int z=0; z<NS; ++z){
      const float* p = P + ((size_t)z*M_ + row)*D_;
      v0 += p[tid]; v1 += p[tid+256]; v2 += p[tid+512];
    }
    x[tid] = v0; x[tid+256] = v1; x[tid+512] = v2;
  }
  float ss = v0*v0 + v1*v1 + v2*v2;
  #pragma unroll
  for (int m=1; m<64; m<<=1) ss += __shfl_xor(ss, m, 64);
  __shared__ float wsum[4];
  __shared__ float rbuf;
  if ((tid & 63) == 0) wsum[tid>>6] = ss;
  __syncthreads();
  if (tid == 0) rbuf = rsqrtf((wsum[0]+wsum[1]+wsum[2]+wsum[3])*(1.0f/D_) + 1.1920929e-07f);
  __syncthreads();
  float r = rbuf;
  unsigned short* o = h + (size_t)row*D_;
  o[tid]     = f2bf(v0*r);
  o[tid+256] = f2bf(v1*r);
  o[tid+512] = f2bf(v2*r);
}

// ---------------- final split-K reduce: s += sum of 4 partials ----------------
__global__ __launch_bounds__(256) void reduce_k(float* __restrict__ s,
                                                const float* __restrict__ P){
  int idx = blockIdx.x*256 + threadIdx.x;          // over M*D/4 float4s
  float4 v = ((float4*)s)[idx];
  #pragma unroll
  for (int z=0; z<4; ++z){
    float4 p = ((const float4*)(P + (size_t)z*M_*D_))[idx];
    v.x += p.x; v.y += p.y; v.z += p.z; v.w += p.w;
  }
  ((float4*)s)[idx] = v;
}

// ---------------- bf16 GEMM: C[M,N] = A[M,K] @ W[N,K]^T + bias, fused epilogues ----
// MODE 0: qkv — q,k get RoPE applied in-register (partner col+32 is acc[mi][ni+2]),
//         written bf16 to outq/outk in [bh][i][64]; v cols -> outb bf16 [bh][j][64].
// MODE 1: attn out proj — SPLIT=1: resid += C; SPLIT>1: partials[z] = C (no atomics)
// MODE 2: outb = bf16(gelu(C))(fc1)
// MODE 3: fc2 — same as MODE 1
// TM: 128 or 64 (M rows per block). SPLIT: split-K factor (partial-buffer epilogue if >1).
// XCD-chunked block remap (bijective; all grids %8==0): each XCD gets a contiguous
// lid-chunk decoded y-fastest so its working set (A-panel group + few W panels) fits L2.
template<int MODE, int TM, int SPLIT>
__global__ __launch_bounds__(256) void gemm_bt(const unsigned short* __restrict__ A,
    const unsigned short* __restrict__ W, const float* __restrict__ bias,
    unsigned short* __restrict__ outb, float* __restrict__ resid,
    unsigned short* __restrict__ outq, unsigned short* __restrict__ outk,
    const float2* __restrict__ rtab, int N, int K){
  constexpr int MI = TM/32;
  __shared__ __align__(16) short sm[2][(TM+128)*32];
  const int tid  = threadIdx.x;
  const int wave = tid >> 6, lane = tid & 63;
  int bx, by, bz;
  {
    const int nx = gridDim.x, ny = gridDim.y;
    const int flat = blockIdx.x + nx*(blockIdx.y + ny*blockIdx.z);
    const int q = (nx*ny*gridDim.z) >> 3;          // blocks per XCD chunk
    const int lid = (flat & 7)*q + (flat >> 3);
    bz = lid/(nx*ny); const int rem = lid - bz*(nx*ny);
    bx = rem/ny; by = rem - bx*ny;                 // y-fastest within chunk
  }
  const int m0 = by*TM, n0 = bx << 7;
  const int KB = K / SPLIT;
  const int kbase = bz * KB;
  const int wm = (wave >> 1)*(TM/2), wn = (wave & 1) << 6;
  const int lrow = lane & 15, ko = (lane >> 4) << 3;
  f32x4 acc[MI][4] = {};
  const unsigned short* Ag = A + (size_t)(m0 + (tid>>2))*K + kbase + ((tid&3)<<3);
  const unsigned short* Wg = W + (size_t)(n0 + (tid>>2))*K + kbase + ((tid&3)<<3);
  const size_t hstep = (size_t)64*K;
  const int nk = KB >> 5;
  {  // prologue stage into buf 0
    short* As = sm[0]; short* Bs = sm[0] + TM*32;
    gl_lds16(Ag, &As[tid*8]);
    if (TM == 128) gl_lds16(Ag + hstep, &As[(tid+256)*8]);
    gl_lds16(Wg, &Bs[tid*8]);
    gl_lds16(Wg + hstep, &Bs[(tid+256)*8]);
  }
  for (int it = 0; it < nk; ++it){
    __syncthreads();                       // drains vmcnt -> buf (it&1) ready
    if (it + 1 < nk){                      // async-prefetch next tile, overlaps MFMA below
      short* As = sm[(it&1)^1]; short* Bs = As + TM*32;
      const int kt = (it+1) << 5;
      gl_lds16(Ag + kt, &As[tid*8]);
      if (TM == 128) gl_lds16(Ag + hstep + kt, &As[(tid+256)*8]);
      gl_lds16(Wg + kt, &Bs[tid*8]);
      gl_lds16(Wg + hstep + kt, &Bs[(tid+256)*8]);
    }
    const short* As = sm[it&1]; const short* Bs = As + TM*32;
    bf16x8 af[MI], bv[4];
    #pragma unroll
    for (int i=0;i<MI;++i) af[i] = *(const bf16x8*)&As[((wm + i*16 + lrow) << 5) + ko];
    #pragma unroll
    for (int i=0;i<4;++i)  bv[i] = *(const bf16x8*)&Bs[((wn + i*16 + lrow) << 5) + ko];
    #pragma unroll
    for (int mi=0;mi<MI;++mi)
      #pragma unroll
      for (int ni=0;ni<4;++ni)
        acc[mi][ni] = __builtin_amdgcn_mfma_f32_16x16x32_bf16(af[mi], bv[ni], acc[mi][ni], 0, 0, 0);
  }
  if (MODE == 0){
    // rope-fused epilogue: process (ni, ni+2) pairs = (d, d+32) of one head
    #pragma unroll
    for (int ni=0; ni<2; ++ni){
      const int col0 = n0 + wn + ni*16 + lrow;       // d = d0 in [0,32)
      const int d0 = ni*16 + lrow;
      const float b0 = bias[col0], b2 = bias[col0 + 32];
      #pragma unroll
      for (int mi=0; mi<MI; ++mi){
        const int rw = m0 + wm + mi*16 + ((lane >> 4) << 2);
        #pragma unroll
        for (int r=0; r<4; ++r){
          const int rowg = rw + r;
          const int bI = rowg >> 10, iI = rowg & (L_-1);
          const float v0 = acc[mi][ni][r]   + b0;
          const float v2 = acc[mi][ni+2][r] + b2;
          if (col0 < 2*D_){
            const bool isq = (col0 < D_);
            const int  h   = (isq ? col0 : col0 - D_) >> 6;
            const float2 cssn = rtab[iI*32 + d0];
            const float o0 = v0*cssn.x - v2*cssn.y;   // d<32: q*c - q[d+32]*s
            const float o2 = v2*cssn.x + v0*cssn.y;   // d>=32: q*c + q[d-32]*s
            unsigned short* dst = (isq ? outq : outk)
                + ((((size_t)(bI*H_ + h)) << 10 | iI) << 6);
            dst[d0]      = f2bf(o0);
            dst[d0 + 32] = f2bf(o2);
          } else {
            const int h = (col0 - 2*D_) >> 6;
            unsigned short* dst = outb + ((((size_t)(bI*H_ + h)) << 10 | iI) << 6);
            dst[d0]      = f2bf(v0);
            dst[d0 + 32] = f2bf(v2);
          }
        }
      }
    }
  } else {
    #pragma unroll
    for (int ni=0;ni<4;++ni){
      const int col = n0 + wn + ni*16 + lrow;
      const float bb = (SPLIT == 1 || bz == 0) ? bias[col] : 0.f;
      #pragma unroll
      for (int mi=0;mi<MI;++mi){
        const int rw = m0 + wm + mi*16 + ((lane >> 4) << 2);
        #pragma unroll
        for (int r=0;r<4;++r){
          float v = acc[mi][ni][r] + bb;
          if (MODE == 2){
            float g = 0.5f * v * (1.0f + erff(v * 0.70710678118654752f));
            outb[(size_t)(rw + r)*N + col] = f2bf(g);
          } else {
            if (SPLIT == 1) resid[(size_t)(rw + r)*D_ + col] += v;
            else            resid[((size_t)bz*M_ + (rw + r))*D_ + col] = v;
          }
        }
      }
    }
  }
}

// ---------------- windowed MFMA attention, 32-query tiles ----------------
// Per block: one (bh, 32-query tile). K-strip of 288 keys staged bf16 in LDS
// (precomputed bf16 K, no conversion), QK^T and PV via 16x16x32 bf16 MFMA.
// V (precomputed bf16) reuses the K buffer after softmax.
// XCD-chunked remap, x-fastest: each XCD owns ~3 consecutive bh -> K/V/bias L2-resident.
__global__ __launch_bounds__(256) void attn_k(const unsigned short* __restrict__ qr,
    const unsigned short* __restrict__ kr, const unsigned short* __restrict__ vr,
    const float* __restrict__ bias, unsigned short* __restrict__ ybf, int layer){
  __shared__ __align__(16) short kb[288*72];   // K then V, row stride 72 (+8 pad) = 41472 B
  __shared__ __align__(16) float sc[32*304];   // scores f32; probs bf16 alias below
  short* ps = (short*)sc;                      // [32][296] bf16 (stride 296: conflict-free b128)
  const int tid  = threadIdx.x;
  const int wave = tid >> 6, lane = tid & 63;
  const int quad = lane >> 4, lrow = lane & 15;
  int bx, by;
  {
    const int nx = gridDim.x;
    const int flat = blockIdx.x + nx*blockIdx.y;
    const int q = (nx*gridDim.y) >> 3;
    const int lid = (flat & 7)*q + (flat >> 3);
    by = lid/nx; bx = lid - by*nx;               // x-fastest within chunk
  }
  const int bh = by, b = bh / H_, h = bh - b*H_;
  const int i0 = bx * 32, jb = i0 - WIN_;

  // Q fragments for both 16-row m-tiles: A[m=lrow][k=quad*8+j], two K=32 halves
  bf16x8 qf[2][2];
  #pragma unroll
  for (int mt=0; mt<2; ++mt){
    const unsigned short* qrow = qr + (((size_t)bh*L_ + i0 + mt*16 + lrow) << 6) + quad*8;
    qf[mt][0] = *(const bf16x8*)qrow;
    qf[mt][1] = *(const bf16x8*)(qrow + 32);
  }
  // stage K strip (288 rows x 64 bf16), zero-filled outside [0,L)
  {
    const int r0 = tid >> 3, seg = tid & 7;
    #pragma unroll
    for (int p=0; p<9; ++p){
      const int r = r0 + p*32;
      const int jg = jb + r;
      bf16x8 z;
      #pragma unroll
      for (int q=0;q<8;++q) z[q] = 0;
      if ((unsigned)jg < L_) z = *(const bf16x8*)(kr + (((size_t)bh*L_ + jg) << 6) + seg*8);
      *(bf16x8*)&kb[r*72 + seg*8] = z;
    }
  }
  __syncthreads();
  // QK^T: 18 key-chunks of 16, round-robin over waves; each wave does both m-tiles
  for (int c = wave; c < 18; c += 4){
    const int krow = c*16 + lrow;
    const bf16x8 kf0 = *(const bf16x8*)&kb[krow*72 + quad*8];
    const bf16x8 kf1 = *(const bf16x8*)&kb[krow*72 + 32 + quad*8];
    const int jj = c*16 + lrow, jg = jb + jj;
    #pragma unroll
    for (int mt=0; mt<2; ++mt){
      f32x4 cc = {0.f,0.f,0.f,0.f};
      cc = __builtin_amdgcn_mfma_f32_16x16x32_bf16(qf[mt][0], kf0, cc, 0, 0, 0);
      cc = __builtin_amdgcn_mfma_f32_16x16x32_bf16(qf[mt][1], kf1, cc, 0, 0, 0);
      #pragma unroll
      for (int r=0;r<4;++r){
        const int row = mt*16 + quad*4 + r;
        const int rel = jj - row;             // j - i + 128
        float v = -1e30f;
        if (rel >= 0 && rel <= 256 && (unsigned)jg < L_)
          v = cc[r]*0.125f + bias[(((size_t)(layer*B_ + b))*L_ + i0 + row)*W2_ + rel];
        sc[row*304 + jj] = v;
      }
    }
  }
  __syncthreads();
  // softmax: thread group of 16 handles rows qq and qq+16
  const int qq = tid >> 4, tj = tid & 15;
  float ev[2][18];
  #pragma unroll
  for (int g=0; g<2; ++g)
    #pragma unroll
    for (int c=0;c<18;++c) ev[g][c] = sc[(qq + g*16)*304 + c*16 + tj];
  __syncthreads();                 // all sc reads done before ps alias-writes
  #pragma unroll
  for (int g=0; g<2; ++g){
    float mx = -3.0e38f;
    #pragma unroll
    for (int c=0;c<18;++c) mx = fmaxf(mx, ev[g][c]);
    #pragma unroll
    for (int m=1; m<16; m<<=1) mx = fmaxf(mx, __shfl_xor(mx, m, 16));
    float sm = 0.f;
    #pragma unroll
    for (int c=0;c<18;++c){ float e = __expf(ev[g][c] - mx); ev[g][c] = e; sm += e; }
    #pragma unroll
    for (int m=1; m<16; m<<=1) sm += __shfl_xor(sm, m, 16);
    const float inv = 1.0f / sm;
    #pragma unroll
    for (int c=0;c<18;++c) ps[(qq + g*16)*296 + c*16 + tj] = (short)f2bf(ev[g][c]*inv);
  }
  // stage V into kb (zero-fill: ps~0 rows must not meet inf/NaN)
  {
    const int r0 = tid >> 3, seg = tid & 7;
    #pragma unroll
    for (int p=0; p<9; ++p){
      const int r = r0 + p*32;
      const int jg = jb + r;
      bf16x8 z;
      #pragma unroll
      for (int q=0;q<8;++q) z[q] = 0;
      if ((unsigned)jg < L_) z = *(const bf16x8*)(vr + (((size_t)bh*L_ + jg) << 6) + seg*8);
      *(bf16x8*)&kb[r*72 + seg*8] = z;
    }
  }
  __syncthreads();
  // PV: O[32][64] = P[32x288] @ V[288x64]; wave owns d-tile [wave*16, wave*16+16)
  f32x4 o0 = {0.f,0.f,0.f,0.f}, o1 = {0.f,0.f,0.f,0.f};
  for (int kc=0; kc<9; ++kc){
    bf16x8 bf;
    #pragma unroll
    for (int j=0;j<8;++j) bf[j] = kb[(kc*32 + quad*8 + j)*72 + wave*16 + lrow];
    const bf16x8 a0 = *(const bf16x8*)&ps[lrow*296 + kc*32 + quad*8];
    const bf16x8 a1 = *(const bf16x8*)&ps[(16 + lrow)*296 + kc*32 + quad*8];
    o0 = __builtin_amdgcn_mfma_f32_16x16x32_bf16(a0, bf, o0, 0, 0, 0);
    o1 = __builtin_amdgcn_mfma_f32_16x16x32_bf16(a1, bf, o1, 0, 0, 0);
  }
  #pragma unroll
  for (int r=0;r<4;++r){
    const int row = quad*4 + r;
    ybf[((size_t)(b*L_ + i0 + row))*D_ + h*64 + wave*16 + lrow]      = f2bf(o0[r]);
    ybf[((size_t)(b*L_ + i0 + 16 + row))*D_ + h*64 + wave*16 + lrow] = f2bf(o1[r]);
  }
}

extern "C" void kernel_launch(void* const* d_in, const int* in_sizes, int n_in,
                              void* d_out, int out_size, void* d_ws, size_t ws_size,
                              hipStream_t stream){
  (void)in_sizes; (void)n_in; (void)out_size; (void)ws_size;
  const float* s_in  = (const float*)d_in[0];
  const float* pair  = (const float*)d_in[1];
  const float* qkv_w = (const float*)d_in[2];
  const float* qkv_b = (const float*)d_in[3];
  const float* out_w = (const float*)d_in[4];
  const float* out_b = (const float*)d_in[5];
  const float* fc1_w = (const float*)d_in[6];
  const float* fc1_b = (const float*)d_in[7];
  const float* fc2_w = (const float*)d_in[8];
  const float* fc2_b = (const float*)d_in[9];
  const float* ln_g  = (const float*)d_in[10];
  const float* ln_b  = (const float*)d_in[11];
  const float* pb_w  = (const float*)d_in[12];
  const float* pb_b  = (const float*)d_in[13];
  float* s = (float*)d_out;                    // residual stream lives in d_out

  char* ws = (char*)d_ws;
  size_t off = 0;
  auto take = [&](size_t bytes)->char*{
    char* p = ws + off; off += (bytes + 255) & ~(size_t)255; return p;
  };
  // NOTE: wqkv..wfc2 must stay contiguous (prologue_k writes via one base ptr);
  // all four sizes are exact multiples of 256 B.
  unsigned short* wqkv = (unsigned short*)take((size_t)NL_*3*D_*D_*2);
  unsigned short* wout = (unsigned short*)take((size_t)NL_*D_*D_*2);
  unsigned short* wfc1 = (unsigned short*)take((size_t)NL_*MLP_*D_*2);
  unsigned short* wfc2 = (unsigned short*)take((size_t)NL_*D_*MLP_*2);
  float*          bw   = (float*)take((size_t)NL_*B_*L_*W2_*4);
  unsigned short* hbf  = (unsigned short*)take((size_t)M_*D_*2);
  unsigned short* qrb  = (unsigned short*)take((size_t)B_*H_*L_*DH_*2);
  unsigned short* krb  = (unsigned short*)take((size_t)B_*H_*L_*DH_*2);
  unsigned short* vrb  = (unsigned short*)take((size_t)B_*H_*L_*DH_*2);
  unsigned short* ybf  = (unsigned short*)take((size_t)M_*D_*2);
  unsigned short* gbf  = (unsigned short*)take((size_t)M_*MLP_*2);
  float2*         rtab = (float2*)take((size_t)L_*32*sizeof(float2));
  float*          pacc = (float*)take((size_t)4*M_*D_*4);   // split-K partials

  hipMemcpyAsync(s, s_in, (size_t)M_*D_*sizeof(float), hipMemcpyDeviceToDevice, stream);

  prologue_k<<<PB_BLKS_ + RT_BLKS_ + CVT_Q3_/256, 256, 0, stream>>>(
      pair, ln_g, ln_b, pb_w, pb_b, bw, rtab,
      qkv_w, out_w, fc1_w, fc2_w, wqkv);

  for (int l=0; l<NL_; ++l){
    if (l == 0) rmsnorm_k<0><<<M_, 256, 0, stream>>>(s, nullptr, hbf);
    else        rmsnorm_k<4><<<M_, 256, 0, stream>>>(s, pacc, hbf);   // fold prev fc2 partials
    gemm_bt<0,128,1><<<dim3((3*D_)/128, M_/128), 256, 0, stream>>>(
        hbf, wqkv + (size_t)l*3*D_*D_, qkv_b + l*3*D_, vrb, nullptr, qrb, krb, rtab, 3*D_, D_);
    attn_k<<<dim3(L_/32, B_*H_), 256, 0, stream>>>(qrb, krb, vrb, bw, ybf, l);
    gemm_bt<1,64,2><<<dim3(D_/128, M_/64, 2), 256, 0, stream>>>(
        ybf, wout + (size_t)l*D_*D_, out_b + l*D_, nullptr, pacc, nullptr, nullptr, nullptr, D_, D_);
    rmsnorm_k<2><<<M_, 256, 0, stream>>>(s, pacc, hbf);               // fold out-proj partials
    gemm_bt<2,128,1><<<dim3(MLP_/128, M_/128), 256, 0, stream>>>(
        hbf, wfc1 + (size_t)l*MLP_*D_, fc1_b + l*MLP_, gbf, nullptr, nullptr, nullptr, nullptr, MLP_, D_);
    gemm_bt<3,64,4><<<dim3(D_/128, M_/64, 4), 256, 0, stream>>>(
        gbf, wfc2 + (size_t)l*D_*MLP_, fc2_b + l*D_, nullptr, pacc, nullptr, nullptr, nullptr, D_, MLP_);
  }
  reduce_k<<<(M_*D_/4)/256, 256, 0, stream>>>(s, pacc);               // fold last fc2 partials
}